// Round 1
// baseline (1224.020 us; speedup 1.0000x reference)
//
#include <hip/hip_runtime.h>
#include <math.h>

#define DEV_INLINE __device__ __forceinline__

// ---------------- workspace layout (float offsets) ----------------
// A : 16MB scratch (a_ln1 -> fsr -> xz -> ff1)
// B : 8MB  (xm_conv -> a7)
// C : 8MB  (dt)
// D : 8MB  (scan y)
// E : fw, F : fs_small, G : fc/m, H : x(res), I : xn, J : mamba sum
static constexpr size_t OFF_A  = 0;         // 4,194,304 floats
static constexpr size_t OFF_B  = 4194304;   // 2,097,152
static constexpr size_t OFF_C  = 6291456;   // 2,097,152
static constexpr size_t OFF_D  = 8388608;   // 2,097,152
static constexpr size_t OFF_E  = 10485760;  // 1,048,576
static constexpr size_t OFF_F  = 11534336;  //   524,288
static constexpr size_t OFF_G  = 12058624;  // 1,048,576
static constexpr size_t OFF_H  = 13107200;  // 1,048,576
static constexpr size_t OFF_I  = 14155776;  // 1,048,576
static constexpr size_t OFF_J  = 15204352;  // 1,048,576
static constexpr size_t OFF_K1 = 16252928;  //   131,072 (a_ln2)
static constexpr size_t OFF_K2 = 16384000;  //   196,608 (xdbl)
static constexpr size_t OFF_S1 = 16580608;  //    16,384 (se partials)
static constexpr size_t OFF_S2 = 16596992;  //     1,024 (se)

// ---------------- block-wide sum, blockDim == 256 ----------------
DEV_INLINE float blockSum256(float v) {
  __shared__ float sh[4];
  int lane = threadIdx.x & 63;
  int w    = threadIdx.x >> 6;
#pragma unroll
  for (int o = 32; o; o >>= 1) v += __shfl_down(v, o, 64);
  __syncthreads();                 // protect sh from previous call
  if (lane == 0) sh[w] = v;
  __syncthreads();
  return sh[0] + sh[1] + sh[2] + sh[3];
}

// ---------------- generic row LayerNorm (L <= 1024) ----------------
__global__ void k_layernorm(const float* __restrict__ in, float* __restrict__ out,
                            const float* __restrict__ g, const float* __restrict__ b,
                            int L) {
  __shared__ float row[1024];
  size_t rid = blockIdx.x;
  const float* x = in + rid * (size_t)L;
  float s = 0.f;
  for (int i = threadIdx.x; i < L; i += 256) { float v = x[i]; row[i] = v; s += v; }
  float mean = blockSum256(s) / (float)L;
  float vs = 0.f;
  for (int i = threadIdx.x; i < L; i += 256) { float d = row[i] - mean; vs += d * d; }
  float var = blockSum256(vs) / (float)L;
  float rstd = rsqrtf(var + 1e-5f);
  for (int i = threadIdx.x; i < L; i += 256)
    out[rid * (size_t)L + i] = (row[i] - mean) * rstd * g[i] + b[i];
}

// ---------------- tiled f32 GEMM: C[M,N] = epi(A[M,K] @ W[N,K]^T) -----------
// ACT: 0 none, 1 exact gelu, 2 softplus
template <int ACT, bool ACCUM, bool RESADD>
__global__ __launch_bounds__(256) void k_gemm(
    const float* __restrict__ A, int lda,
    const float* __restrict__ W, int ldw,
    const float* __restrict__ bias,
    float* __restrict__ C, int ldc,
    const float* __restrict__ res,
    int M, int N, int K) {
  __shared__ float As[16][68];
  __shared__ float Ws[16][68];
  int tid = threadIdx.x;
  int bm = blockIdx.y << 6, bn = blockIdx.x << 6;
  int tx = tid & 15, ty = tid >> 4;
  int m0 = ty << 2, n0 = tx << 2;
  float acc[4][4] = {};
  int kk = tid & 15, rr = tid >> 4;
  for (int k0 = 0; k0 < K; k0 += 16) {
#pragma unroll
    for (int j = 0; j < 4; j++) {
      int m = (rr << 2) + j;
      As[kk][m] = A[(size_t)(bm + m) * lda + k0 + kk];
      int n = (rr << 2) + j;
      Ws[kk][n] = (bn + n < N) ? W[(size_t)(bn + n) * ldw + k0 + kk] : 0.f;
    }
    __syncthreads();
#pragma unroll
    for (int q = 0; q < 16; q++) {
      float4 av = *reinterpret_cast<const float4*>(&As[q][m0]);
      float4 bv = *reinterpret_cast<const float4*>(&Ws[q][n0]);
      float a[4] = {av.x, av.y, av.z, av.w};
      float b[4] = {bv.x, bv.y, bv.z, bv.w};
#pragma unroll
      for (int i = 0; i < 4; i++)
#pragma unroll
        for (int j = 0; j < 4; j++) acc[i][j] += a[i] * b[j];
    }
    __syncthreads();
  }
#pragma unroll
  for (int i = 0; i < 4; i++) {
#pragma unroll
    for (int j = 0; j < 4; j++) {
      int row = bm + m0 + i, col = bn + n0 + j;
      if (col < N) {
        float v = acc[i][j];
        if (bias) v += bias[col];
        if (ACT == 1) v = 0.5f * v * (1.f + erff(v * 0.70710678118f));
        if (ACT == 2) v = (v > 20.f) ? v : log1pf(expf(v));
        size_t oi = (size_t)row * ldc + col;
        if (ACCUM) v += C[oi];
        if (RESADD) v += res[oi];
        C[oi] = v;
      }
    }
  }
}

// ---------------- linear resize T 512 -> 1024 (half-pixel, edge clamp) ------
__global__ void k_resize(const float* __restrict__ fs, float* __restrict__ out) {
  int idx = blockIdx.x * 256 + threadIdx.x;  // (b,t,e): 4*1024*256
  int e = idx & 255, t = (idx >> 8) & 1023, b = idx >> 18;
  int j = t >> 1;
  int j0, j1; float w0, w1;
  if ((t & 1) == 0) { j0 = j > 0 ? j - 1 : 0; j1 = j; w0 = 0.25f; w1 = 0.75f; }
  else              { j0 = j; j1 = j < 511 ? j + 1 : 511; w0 = 0.75f; w1 = 0.25f; }
  out[idx] = w0 * fs[((size_t)(b << 9) + j0) * 256 + e] +
             w1 * fs[((size_t)(b << 9) + j1) * 256 + e];
}

// ---------------- SE: partial mean over T ----------------
__global__ void k_se_part(const float* __restrict__ fc, float* __restrict__ part) {
  int b = blockIdx.y, chunk = blockIdx.x, e = threadIdx.x;
  float s = 0.f;
  for (int j = 0; j < 64; j++) {
    int t = chunk * 64 + j;
    s += fc[((size_t)(b << 10) + t) * 256 + e];
  }
  part[(size_t)(b * 16 + chunk) * 256 + e] = s;
}

// ---------------- SE: finish mean + 2-layer MLP + sigmoid ----------------
__global__ void k_se_fin(const float* __restrict__ part, const float* __restrict__ W1,
                         const float* __restrict__ W2, float* __restrict__ se) {
  int b = blockIdx.x, tid = threadIdx.x;
  __shared__ float mean[256];
  __shared__ float hid[16];
  float s = 0.f;
  for (int c = 0; c < 16; c++) s += part[(size_t)(b * 16 + c) * 256 + tid];
  mean[tid] = s * (1.f / 1024.f);
  __syncthreads();
  int o = tid >> 4, l = tid & 15;
  float p = 0.f;
  for (int e = l; e < 256; e += 16) p += mean[e] * W1[o * 256 + e];
  p += __shfl_xor(p, 1, 64); p += __shfl_xor(p, 2, 64);
  p += __shfl_xor(p, 4, 64); p += __shfl_xor(p, 8, 64);
  if (l == 0) hid[o] = fmaxf(p, 0.f);
  __syncthreads();
  float s2 = 0.f;
  for (int o2 = 0; o2 < 16; o2++) s2 += hid[o2] * W2[tid * 16 + o2];
  se[b * 256 + tid] = 1.f / (1.f + expf(-s2));
}

// ---------------- fused SE-scale + LN_f + LN_1 (row of 256) ----------------
__global__ void k_se_ln(const float* __restrict__ fc, const float* __restrict__ se,
                        const float* __restrict__ gf, const float* __restrict__ bf,
                        const float* __restrict__ g1, const float* __restrict__ b1,
                        float* __restrict__ xout, float* __restrict__ xnout) {
  size_t rid = blockIdx.x;  // b*1024 + t
  int b = (int)(rid >> 10);
  int e = threadIdx.x;
  float v = fc[rid * 256 + e] * se[b * 256 + e];
  float m1 = blockSum256(v) * (1.f / 256.f);
  float d = v - m1;
  float var = blockSum256(d * d) * (1.f / 256.f);
  float x = d * rsqrtf(var + 1e-5f) * gf[e] + bf[e];
  xout[rid * 256 + e] = x;
  float m2 = blockSum256(x) * (1.f / 256.f);
  float d2 = x - m2;
  float v2 = blockSum256(d2 * d2) * (1.f / 256.f);
  xnout[rid * 256 + e] = d2 * rsqrtf(v2 + 1e-5f) * g1[e] + b1[e];
}

// ---------------- causal / anti-causal depthwise conv + silu ----------------
__global__ void k_conv(const float* __restrict__ xz, const float* __restrict__ cw,
                       const float* __restrict__ cb, float* __restrict__ out, int dir) {
  int idx = blockIdx.x * 256 + threadIdx.x;  // (b,t,d): 4*1024*512
  int d = idx & 511, t = (idx >> 9) & 1023, b = idx >> 19;
  float acc = cb[d];
#pragma unroll
  for (int k = 0; k < 4; k++) {
    int tt = dir ? (t + 3 - k) : (t + k - 3);
    if (tt >= 0 && tt < 1024)
      acc += xz[(((size_t)(b << 10) + tt) << 10) + d] * cw[(d << 2) + k];
  }
  out[(size_t)idx] = acc / (1.f + expf(-acc));  // silu
}

// ---------------- selective scan ----------------
// thread = (d_in_tile, n); nn = tid&15, di = tid>>4; block handles (b, 16 d's)
__global__ __launch_bounds__(256) void k_scan(
    const float* __restrict__ u, const float* __restrict__ dtb,
    const float* __restrict__ xdbl, const float* __restrict__ A_log,
    const float* __restrict__ Dp, float* __restrict__ y, int dir) {
  __shared__ float su[64][16], sdt[64][16], sB[64][16], sC[64][16], sy[64][16];
  int b = blockIdx.y, d0 = blockIdx.x << 4;
  int tid = threadIdx.x, nn = tid & 15, di = tid >> 4;
  int d = d0 + di;
  float a_co = -expf(A_log[d * 16 + nn]);
  float dcoef = Dp[d];
  float h = 0.f;
  int colL = tid & 15, rowL = tid >> 4;
  for (int c = 0; c < 16; c++) {
    for (int r = rowL; r < 64; r += 16) {
      int s = c * 64 + r;
      int t = dir ? (1023 - s) : s;
      size_t rb = (size_t)(b << 10) + t;
      su[r][colL]  = u[rb * 512 + d0 + colL];
      sdt[r][colL] = dtb[rb * 512 + d0 + colL];
      sB[r][colL]  = xdbl[rb * 48 + 16 + colL];
      sC[r][colL]  = xdbl[rb * 48 + 32 + colL];
    }
    __syncthreads();
    for (int j = 0; j < 64; j++) {
      float dtv = sdt[j][di];
      float uv = su[j][di];
      float bv = sB[j][nn];
      float cv = sC[j][nn];
      h = __expf(dtv * a_co) * h + dtv * bv * uv;
      float p = h * cv;
      p += __shfl_xor(p, 1, 64); p += __shfl_xor(p, 2, 64);
      p += __shfl_xor(p, 4, 64); p += __shfl_xor(p, 8, 64);
      if (nn == 0) sy[j][di] = p + uv * dcoef;
    }
    __syncthreads();
    for (int r = rowL; r < 64; r += 16) {
      int s = c * 64 + r;
      int t = dir ? (1023 - s) : s;
      y[((size_t)(b << 10) + t) * 512 + d0 + colL] = sy[r][colL];
    }
    __syncthreads();
  }
}

// ---------------- a7 = y * silu(z) ----------------
__global__ void k_a7(const float* __restrict__ xz, const float* __restrict__ y,
                     float* __restrict__ out) {
  int idx = blockIdx.x * 256 + threadIdx.x;  // (b,t,d)
  int d = idx & 511, t = (idx >> 9) & 1023, b = idx >> 19;
  float z = xz[(((size_t)(b << 10) + t) << 10) + 512 + d];
  out[(size_t)idx] = y[(size_t)idx] * (z / (1.f + expf(-z)));
}

// ---------------- host-side GEMM dispatcher ----------------
static inline void gemm_launch(hipStream_t st, int act, bool accum, bool resadd,
                               const float* A, int lda, const float* W, int ldw,
                               const float* bias, float* C, int ldc,
                               const float* res, int M, int N, int K) {
  dim3 g((N + 63) / 64, M / 64), bl(256);
  if (resadd)        hipLaunchKernelGGL((k_gemm<0, false, true>),  g, bl, 0, st, A, lda, W, ldw, bias, C, ldc, res, M, N, K);
  else if (act == 1) hipLaunchKernelGGL((k_gemm<1, false, false>), g, bl, 0, st, A, lda, W, ldw, bias, C, ldc, res, M, N, K);
  else if (act == 2) hipLaunchKernelGGL((k_gemm<2, false, false>), g, bl, 0, st, A, lda, W, ldw, bias, C, ldc, res, M, N, K);
  else if (accum)    hipLaunchKernelGGL((k_gemm<0, true, false>),  g, bl, 0, st, A, lda, W, ldw, bias, C, ldc, res, M, N, K);
  else               hipLaunchKernelGGL((k_gemm<0, false, false>), g, bl, 0, st, A, lda, W, ldw, bias, C, ldc, res, M, N, K);
}

extern "C" void kernel_launch(void* const* d_in, const int* in_sizes, int n_in,
                              void* d_out, int out_size, void* d_ws, size_t ws_size,
                              hipStream_t stream) {
  const float* f_wavlm = (const float*)d_in[0];
  const float* f_sinc  = (const float*)d_in[1];
  const float* ln_w_g  = (const float*)d_in[2];
  const float* ln_w_b  = (const float*)d_in[3];
  const float* ln_s_g  = (const float*)d_in[4];
  const float* ln_s_b  = (const float*)d_in[5];
  const float* W_wp    = (const float*)d_in[6];
  const float* b_wp    = (const float*)d_in[7];
  const float* W_sp    = (const float*)d_in[8];
  const float* b_sp    = (const float*)d_in[9];
  const float* W_fuse  = (const float*)d_in[10];
  const float* b_fuse  = (const float*)d_in[11];
  const float* W_se1   = (const float*)d_in[12];
  const float* W_se2   = (const float*)d_in[13];
  const float* ln_f_g  = (const float*)d_in[14];
  const float* ln_f_b  = (const float*)d_in[15];
  const float* n1_g    = (const float*)d_in[16];
  const float* n1_b    = (const float*)d_in[17];
  const float* n2_g    = (const float*)d_in[18];
  const float* n2_b    = (const float*)d_in[19];
  const float* W_in    = (const float*)d_in[20];
  const float* conv_w  = (const float*)d_in[21];
  const float* conv_b  = (const float*)d_in[22];
  const float* W_xproj = (const float*)d_in[23];
  const float* W_dt    = (const float*)d_in[24];
  const float* b_dt    = (const float*)d_in[25];
  const float* A_log   = (const float*)d_in[26];
  const float* Dp      = (const float*)d_in[27];
  const float* W_out   = (const float*)d_in[28];
  const float* W_ff1   = (const float*)d_in[29];
  const float* b_ff1   = (const float*)d_in[30];
  const float* W_ff2   = (const float*)d_in[31];
  const float* b_ff2   = (const float*)d_in[32];

  float* ws = (float*)d_ws;
  float* pA  = ws + OFF_A;   // 16MB scratch
  float* pB  = ws + OFF_B;
  float* pC  = ws + OFF_C;
  float* pD  = ws + OFF_D;
  float* pE  = ws + OFF_E;   // fw
  float* pF  = ws + OFF_F;   // fs_small
  float* pG  = ws + OFF_G;   // fc / m
  float* pH  = ws + OFF_H;   // x (res)
  float* pI  = ws + OFF_I;   // xn
  float* pJ  = ws + OFF_J;   // mamba sum
  float* pK1 = ws + OFF_K1;  // a_ln2
  float* pK2 = ws + OFF_K2;  // xdbl
  float* pS1 = ws + OFF_S1;
  float* pS2 = ws + OFF_S2;

  // 1) LN(f_wavlm) -> A ; fw = A @ W_wp^T + b_wp -> E
  hipLaunchKernelGGL(k_layernorm, dim3(4096), dim3(256), 0, stream,
                     f_wavlm, pA, ln_w_g, ln_w_b, 1024);
  gemm_launch(stream, 0, false, false, pA, 1024, W_wp, 1024, b_wp, pE, 256,
              nullptr, 4096, 256, 1024);

  // 2) LN(f_sinc) -> K1 ; fs_small = K1 @ W_sp^T + b_sp -> F
  hipLaunchKernelGGL(k_layernorm, dim3(2048), dim3(256), 0, stream,
                     f_sinc, pK1, ln_s_g, ln_s_b, 64);
  gemm_launch(stream, 0, false, false, pK1, 64, W_sp, 64, b_sp, pF, 256,
              nullptr, 2048, 256, 64);

  // 3) resize -> A[0:1M] ; fc = fw@Wf[:, :256]^T + b + fsr@Wf[:,256:]^T -> G
  hipLaunchKernelGGL(k_resize, dim3(4096), dim3(256), 0, stream, pF, pA);
  gemm_launch(stream, 0, false, false, pE, 256, W_fuse, 512, b_fuse, pG, 256,
              nullptr, 4096, 256, 256);
  gemm_launch(stream, 0, true, false, pA, 256, W_fuse + 256, 512, nullptr, pG, 256,
              nullptr, 4096, 256, 256);

  // 4) SE gate
  hipLaunchKernelGGL(k_se_part, dim3(16, 4), dim3(256), 0, stream, pG, pS1);
  hipLaunchKernelGGL(k_se_fin, dim3(4), dim3(256), 0, stream, pS1, W_se1, W_se2, pS2);

  // 5) x = LN_f(fc*se) -> H ; xn = LN_1(x) -> I
  hipLaunchKernelGGL(k_se_ln, dim3(4096), dim3(256), 0, stream,
                     pG, pS2, ln_f_g, ln_f_b, n1_g, n1_b, pH, pI);

  // 6) xz = xn @ W_in^T -> A (shared by both directions)
  gemm_launch(stream, 0, false, false, pI, 256, W_in, 256, nullptr, pA, 1024,
              nullptr, 4096, 1024, 256);

  // 7) two mamba directions, accumulate into J
  for (int dir = 0; dir < 2; dir++) {
    hipLaunchKernelGGL(k_conv, dim3(8192), dim3(256), 0, stream,
                       pA, conv_w, conv_b, pB, dir);
    gemm_launch(stream, 0, false, false, pB, 512, W_xproj, 512, nullptr, pK2, 48,
                nullptr, 4096, 48, 512);
    gemm_launch(stream, 2, false, false, pK2, 48, W_dt, 16, b_dt, pC, 512,
                nullptr, 4096, 512, 16);
    hipLaunchKernelGGL(k_scan, dim3(32, 4), dim3(256), 0, stream,
                       pB, pC, pK2, A_log, Dp, pD, dir);
    hipLaunchKernelGGL(k_a7, dim3(8192), dim3(256), 0, stream, pA, pD, pB);
    gemm_launch(stream, 0, (dir == 1), false, pB, 512, W_out, 512, nullptr, pJ, 256,
                nullptr, 4096, 256, 512);
  }

  // 8) m = LN_2(mf+mb) -> G ; ff1 = gelu(m @ W_ff1^T + b) -> A
  hipLaunchKernelGGL(k_layernorm, dim3(4096), dim3(256), 0, stream,
                     pJ, pG, n2_g, n2_b, 256);
  gemm_launch(stream, 1, false, false, pG, 256, W_ff1, 256, b_ff1, pA, 1024,
              nullptr, 4096, 1024, 256);

  // 9) out = ff1 @ W_ff2^T + b_ff2 + res
  gemm_launch(stream, 0, false, true, pA, 1024, W_ff2, 1024, b_ff2,
              (float*)d_out, 256, pH, 4096, 256, 1024);
}

// Round 2
// 703.592 us; speedup vs baseline: 1.7397x; 1.7397x over previous
//
#include <hip/hip_runtime.h>
#include <math.h>

#define DEV_INLINE __device__ __forceinline__

// ---------------- workspace layout (float offsets) ----------------
static constexpr size_t OFF_XZ  = 0;         // 4,194,304  ln_wavlm scratch -> xz
static constexpr size_t OFF_U   = 4194304;   // 4,194,304  conv out both dirs -> a7 (in place)
static constexpr size_t OFF_DT  = 8388608;   // 4,194,304  resize scratch -> dt both dirs -> ff1
static constexpr size_t OFF_XD  = 12582912;  //   393,216  xdbl both dirs (8192 x 48)
static constexpr size_t OFF_SP  = 12976128;  // 2,097,152  chunk decay products -> start states
static constexpr size_t OFF_SH  = 15073280;  // 2,097,152  chunk local end states
static constexpr size_t OFF_MO  = 17170432;  // 2,097,152  out GEMM both dirs (8192 x 256)
static constexpr size_t OFF_FW  = 19267584;  // 1,048,576  fw
static constexpr size_t OFF_FS  = 20316160;  //   524,288  fs_small
static constexpr size_t OFF_LNS = 20840448;  //   131,072  ln(f_sinc)
static constexpr size_t OFF_FC  = 20971520;  // 1,048,576  fc -> m
static constexpr size_t OFF_RES = 22020096;  // 1,048,576  x (residual)
static constexpr size_t OFF_XN  = 23068672;  // 1,048,576  xn
static constexpr size_t OFF_SE1 = 24117248;  //    16,384
static constexpr size_t OFF_SE2 = 24133632;  //     1,024

// ---------------- block-wide sum, blockDim == 256 ----------------
DEV_INLINE float blockSum256(float v) {
  __shared__ float sh[4];
  int lane = threadIdx.x & 63;
  int w    = threadIdx.x >> 6;
#pragma unroll
  for (int o = 32; o; o >>= 1) v += __shfl_down(v, o, 64);
  __syncthreads();
  if (lane == 0) sh[w] = v;
  __syncthreads();
  return sh[0] + sh[1] + sh[2] + sh[3];
}

// ---------------- generic row LayerNorm (L <= 1024) ----------------
__global__ void k_layernorm(const float* __restrict__ in, float* __restrict__ out,
                            const float* __restrict__ g, const float* __restrict__ b,
                            int L) {
  __shared__ float row[1024];
  size_t rid = blockIdx.x;
  const float* x = in + rid * (size_t)L;
  float s = 0.f;
  for (int i = threadIdx.x; i < L; i += 256) { float v = x[i]; row[i] = v; s += v; }
  float mean = blockSum256(s) / (float)L;
  float vs = 0.f;
  for (int i = threadIdx.x; i < L; i += 256) { float d = row[i] - mean; vs += d * d; }
  float var = blockSum256(vs) / (float)L;
  float rstd = rsqrtf(var + 1e-5f);
  for (int i = threadIdx.x; i < L; i += 256)
    out[rid * (size_t)L + i] = (row[i] - mean) * rstd * g[i] + b[i];
}

// ---------------- LN over sum of two 256-wide rows (mf+mb) ----------------
__global__ void k_layernorm2(const float* __restrict__ mo, float* __restrict__ out,
                             const float* __restrict__ g, const float* __restrict__ b) {
  size_t rid = blockIdx.x;  // 0..4095
  int e = threadIdx.x;
  float v = mo[rid * 256 + e] + mo[(rid + 4096) * 256 + e];
  float m1 = blockSum256(v) * (1.f / 256.f);
  float d = v - m1;
  float var = blockSum256(d * d) * (1.f / 256.f);
  out[rid * 256 + e] = d * rsqrtf(var + 1e-5f) * g[e] + b[e];
}

// ---------------- tiled f32 GEMM: C[M,N] = epi(A[M,K] @ W[N,K]^T) -----------
// ACT: 0 none, 1 exact gelu, 2 softplus
template <int ACT, bool ACCUM, bool RESADD>
__global__ __launch_bounds__(256) void k_gemm(
    const float* __restrict__ A, int lda,
    const float* __restrict__ W, int ldw,
    const float* __restrict__ bias,
    float* __restrict__ C, int ldc,
    const float* __restrict__ res,
    int M, int N, int K) {
  __shared__ float As[16][68];
  __shared__ float Ws[16][68];
  int tid = threadIdx.x;
  int bm = blockIdx.y << 6, bn = blockIdx.x << 6;
  int tx = tid & 15, ty = tid >> 4;
  int m0 = ty << 2, n0 = tx << 2;
  float acc[4][4] = {};
  int kk = tid & 15, rr = tid >> 4;
  for (int k0 = 0; k0 < K; k0 += 16) {
#pragma unroll
    for (int j = 0; j < 4; j++) {
      int m = (rr << 2) + j;
      As[kk][m] = A[(size_t)(bm + m) * lda + k0 + kk];
      int n = (rr << 2) + j;
      Ws[kk][n] = (bn + n < N) ? W[(size_t)(bn + n) * ldw + k0 + kk] : 0.f;
    }
    __syncthreads();
#pragma unroll
    for (int q = 0; q < 16; q++) {
      float4 av = *reinterpret_cast<const float4*>(&As[q][m0]);
      float4 bv = *reinterpret_cast<const float4*>(&Ws[q][n0]);
      float a[4] = {av.x, av.y, av.z, av.w};
      float b[4] = {bv.x, bv.y, bv.z, bv.w};
#pragma unroll
      for (int i = 0; i < 4; i++)
#pragma unroll
        for (int j = 0; j < 4; j++) acc[i][j] += a[i] * b[j];
    }
    __syncthreads();
  }
#pragma unroll
  for (int i = 0; i < 4; i++) {
#pragma unroll
    for (int j = 0; j < 4; j++) {
      int row = bm + m0 + i, col = bn + n0 + j;
      if (col < N) {
        float v = acc[i][j];
        if (bias) v += bias[col];
        if (ACT == 1) v = 0.5f * v * (1.f + erff(v * 0.70710678118f));
        if (ACT == 2) v = (v > 20.f) ? v : log1pf(expf(v));
        size_t oi = (size_t)row * ldc + col;
        if (ACCUM) v += C[oi];
        if (RESADD) v += res[oi];
        C[oi] = v;
      }
    }
  }
}

// ---------------- linear resize T 512 -> 1024 ----------------
__global__ void k_resize(const float* __restrict__ fs, float* __restrict__ out) {
  int idx = blockIdx.x * 256 + threadIdx.x;
  int e = idx & 255, t = (idx >> 8) & 1023, b = idx >> 18;
  int j = t >> 1;
  int j0, j1; float w0, w1;
  if ((t & 1) == 0) { j0 = j > 0 ? j - 1 : 0; j1 = j; w0 = 0.25f; w1 = 0.75f; }
  else              { j0 = j; j1 = j < 511 ? j + 1 : 511; w0 = 0.75f; w1 = 0.25f; }
  out[idx] = w0 * fs[((size_t)(b << 9) + j0) * 256 + e] +
             w1 * fs[((size_t)(b << 9) + j1) * 256 + e];
}

// ---------------- SE ----------------
__global__ void k_se_part(const float* __restrict__ fc, float* __restrict__ part) {
  int b = blockIdx.y, chunk = blockIdx.x, e = threadIdx.x;
  float s = 0.f;
  for (int j = 0; j < 64; j++) {
    int t = chunk * 64 + j;
    s += fc[((size_t)(b << 10) + t) * 256 + e];
  }
  part[(size_t)(b * 16 + chunk) * 256 + e] = s;
}

__global__ void k_se_fin(const float* __restrict__ part, const float* __restrict__ W1,
                         const float* __restrict__ W2, float* __restrict__ se) {
  int b = blockIdx.x, tid = threadIdx.x;
  __shared__ float mean[256];
  __shared__ float hid[16];
  float s = 0.f;
  for (int c = 0; c < 16; c++) s += part[(size_t)(b * 16 + c) * 256 + tid];
  mean[tid] = s * (1.f / 1024.f);
  __syncthreads();
  int o = tid >> 4, l = tid & 15;
  float p = 0.f;
  for (int e = l; e < 256; e += 16) p += mean[e] * W1[o * 256 + e];
  p += __shfl_xor(p, 1, 64); p += __shfl_xor(p, 2, 64);
  p += __shfl_xor(p, 4, 64); p += __shfl_xor(p, 8, 64);
  if (l == 0) hid[o] = fmaxf(p, 0.f);
  __syncthreads();
  float s2 = 0.f;
  for (int o2 = 0; o2 < 16; o2++) s2 += hid[o2] * W2[tid * 16 + o2];
  se[b * 256 + tid] = 1.f / (1.f + expf(-s2));
}

// ---------------- fused SE-scale + LN_f + LN_1 ----------------
__global__ void k_se_ln(const float* __restrict__ fc, const float* __restrict__ se,
                        const float* __restrict__ gf, const float* __restrict__ bf,
                        const float* __restrict__ g1, const float* __restrict__ b1,
                        float* __restrict__ xout, float* __restrict__ xnout) {
  size_t rid = blockIdx.x;
  int b = (int)(rid >> 10);
  int e = threadIdx.x;
  float v = fc[rid * 256 + e] * se[b * 256 + e];
  float m1 = blockSum256(v) * (1.f / 256.f);
  float d = v - m1;
  float var = blockSum256(d * d) * (1.f / 256.f);
  float x = d * rsqrtf(var + 1e-5f) * gf[e] + bf[e];
  xout[rid * 256 + e] = x;
  float m2 = blockSum256(x) * (1.f / 256.f);
  float d2 = x - m2;
  float v2 = blockSum256(d2 * d2) * (1.f / 256.f);
  xnout[rid * 256 + e] = d2 * rsqrtf(v2 + 1e-5f) * g1[e] + b1[e];
}

// ---------------- depthwise conv + silu, both directions ----------------
__global__ void k_conv(const float* __restrict__ xz, const float* __restrict__ cw,
                       const float* __restrict__ cb, float* __restrict__ out) {
  size_t idx = (size_t)blockIdx.x * 256 + threadIdx.x;  // (dir,b,t,d): 2*4*1024*512
  int d = idx & 511, t = ((int)(idx >> 9)) & 1023, b = ((int)(idx >> 19)) & 3;
  int dir = (int)(idx >> 21);
  float acc = cb[d];
#pragma unroll
  for (int k = 0; k < 4; k++) {
    int tt = dir ? (t + 3 - k) : (t + k - 3);
    if (tt >= 0 && tt < 1024)
      acc += xz[(((size_t)(b << 10) + tt) << 10) + d] * cw[(d << 2) + k];
  }
  out[idx] = acc / (1.f + expf(-acc));  // silu
}

// ---------------- selective scan: chunked parallel, h in registers --------
// layouts: u/dt : [dir][b][t][d] (t in original order), xdbl : [dir*4+b][t][48]
// chunk = 32 steps; scan dim s ascending, t = dir ? 1023-s : s

// Phase A: per (dir,b,chunk,d) compute chunk decay product P[16] and local
// end-state hE[16] (h0=0). SP/SH layout: [((dir*4+b)*32+chunk)*512+d]*16+n
__global__ __launch_bounds__(256) void k_scan_a(
    const float* __restrict__ u, const float* __restrict__ dtb,
    const float* __restrict__ xdbl, const float* __restrict__ A_log,
    float* __restrict__ SP, float* __restrict__ SH) {
  int chunk = blockIdx.x, b = blockIdx.y;
  int dir = blockIdx.z >> 1, dhalf = blockIdx.z & 1;
  int d = (dhalf << 8) + threadIdx.x;
  __shared__ float Bs[32][16];
  for (int i = threadIdx.x; i < 512; i += 256) {
    int j = i >> 4, n = i & 15;
    int s = (chunk << 5) + j;
    int t = dir ? (1023 - s) : s;
    Bs[j][n] = xdbl[((size_t)((dir * 4 + b) * 1024 + t)) * 48 + 16 + n];
  }
  float a[16], h[16], P[16];
#pragma unroll
  for (int n = 0; n < 16; n++) {
    a[n] = -__expf(A_log[d * 16 + n]);
    h[n] = 0.f; P[n] = 1.f;
  }
  __syncthreads();
  size_t base = (size_t)(dir * 4 + b) * 1024;
  int s0 = chunk << 5;
#define ADDR(j) ((base + (dir ? (1023 - (s0 + (j))) : (s0 + (j)))) * 512 + d)
  float dt_n = dtb[ADDR(0)], u_n = u[ADDR(0)];
#pragma unroll 4
  for (int j = 0; j < 32; j++) {
    float dtv = dt_n, uv = u_n;
    if (j < 31) { dt_n = dtb[ADDR(j + 1)]; u_n = u[ADDR(j + 1)]; }
    float c1 = dtv * uv;
    const float4* Bp = reinterpret_cast<const float4*>(&Bs[j][0]);
    float4 b0 = Bp[0], b1 = Bp[1], b2 = Bp[2], b3 = Bp[3];
    float Bv[16] = {b0.x, b0.y, b0.z, b0.w, b1.x, b1.y, b1.z, b1.w,
                    b2.x, b2.y, b2.z, b2.w, b3.x, b3.y, b3.z, b3.w};
#pragma unroll
    for (int n = 0; n < 16; n++) {
      float dA = __expf(dtv * a[n]);
      h[n] = dA * h[n] + c1 * Bv[n];
      P[n] *= dA;
    }
  }
  size_t o = ((size_t)((dir * 4 + b) * 32 + chunk) * 512 + d) * 16;
#pragma unroll
  for (int n = 0; n < 16; n++) { SP[o + n] = P[n]; SH[o + n] = h[n]; }
#undef ADDR
}

// Phase mid: compose chunks sequentially; overwrite SP[c] with chunk-start state
__global__ __launch_bounds__(256) void k_scan_mid(float* __restrict__ SP,
                                                  const float* __restrict__ SH) {
  int dir = blockIdx.z, b = blockIdx.y;
  int d = (blockIdx.x << 4) + (threadIdx.x >> 4);
  int n = threadIdx.x & 15;
  const size_t cs = 512 * 16;
  size_t base = ((size_t)(dir * 4 + b) * 32) * cs + (size_t)d * 16 + n;
  float H = 0.f;
  float Pv = SP[base], hE = SH[base];
  for (int c = 0; c < 32; c++) {
    float Pc = Pv, hc = hE;
    if (c < 31) { Pv = SP[base + (c + 1) * cs]; hE = SH[base + (c + 1) * cs]; }
    SP[base + (size_t)c * cs] = H;
    H = Pc * H + hc;
  }
}

// Phase B: re-run scan with correct start state; y = C.h + u*D; fuse the
// silu(z) gate; write a7 in place over u.
__global__ __launch_bounds__(256) void k_scan_b(
    float* __restrict__ u, const float* __restrict__ dtb,
    const float* __restrict__ xdbl, const float* __restrict__ A_log,
    const float* __restrict__ Dp, const float* __restrict__ xz,
    const float* __restrict__ SP) {
  int chunk = blockIdx.x, b = blockIdx.y;
  int dir = blockIdx.z >> 1, dhalf = blockIdx.z & 1;
  int d = (dhalf << 8) + threadIdx.x;
  __shared__ float Bs[32][16];
  __shared__ float Cs[32][16];
  for (int i = threadIdx.x; i < 512; i += 256) {
    int j = i >> 4, n = i & 15;
    int s = (chunk << 5) + j;
    int t = dir ? (1023 - s) : s;
    size_t row = ((size_t)((dir * 4 + b) * 1024 + t)) * 48;
    Bs[j][n] = xdbl[row + 16 + n];
    Cs[j][n] = xdbl[row + 32 + n];
  }
  float a[16], h[16];
  size_t so = ((size_t)((dir * 4 + b) * 32 + chunk) * 512 + d) * 16;
#pragma unroll
  for (int n = 0; n < 16; n++) {
    a[n] = -__expf(A_log[d * 16 + n]);
    h[n] = SP[so + n];
  }
  float Dval = Dp[d];
  __syncthreads();
  size_t base = (size_t)(dir * 4 + b) * 1024;
  size_t zbase = (size_t)b << 10;
  int s0 = chunk << 5;
#define ADDR(j) ((base + (dir ? (1023 - (s0 + (j))) : (s0 + (j)))) * 512 + d)
#define ZADDR(j) ((((zbase + (dir ? (1023 - (s0 + (j))) : (s0 + (j)))) << 10)) + 512 + d)
  float dt_n = dtb[ADDR(0)], u_n = u[ADDR(0)], z_n = xz[ZADDR(0)];
#pragma unroll 4
  for (int j = 0; j < 32; j++) {
    float dtv = dt_n, uv = u_n, zv = z_n;
    if (j < 31) { dt_n = dtb[ADDR(j + 1)]; u_n = u[ADDR(j + 1)]; z_n = xz[ZADDR(j + 1)]; }
    float c1 = dtv * uv;
    const float4* Bp = reinterpret_cast<const float4*>(&Bs[j][0]);
    const float4* Cp = reinterpret_cast<const float4*>(&Cs[j][0]);
    float4 b0 = Bp[0], b1 = Bp[1], b2 = Bp[2], b3 = Bp[3];
    float4 c0 = Cp[0], c4 = Cp[1], c8 = Cp[2], cc = Cp[3];
    float Bv[16] = {b0.x, b0.y, b0.z, b0.w, b1.x, b1.y, b1.z, b1.w,
                    b2.x, b2.y, b2.z, b2.w, b3.x, b3.y, b3.z, b3.w};
    float Cv[16] = {c0.x, c0.y, c0.z, c0.w, c4.x, c4.y, c4.z, c4.w,
                    c8.x, c8.y, c8.z, c8.w, cc.x, cc.y, cc.z, cc.w};
    float y0 = 0.f, y1 = 0.f, y2 = 0.f, y3 = 0.f;
#pragma unroll
    for (int n = 0; n < 16; n++) {
      float dA = __expf(dtv * a[n]);
      h[n] = dA * h[n] + c1 * Bv[n];
      float p = h[n] * Cv[n];
      if ((n & 3) == 0) y0 += p; else if ((n & 3) == 1) y1 += p;
      else if ((n & 3) == 2) y2 += p; else y3 += p;
    }
    float y = (y0 + y1) + (y2 + y3) + uv * Dval;
    float sig = 1.f / (1.f + expf(-zv));
    u[ADDR(j)] = y * zv * sig;
  }
#undef ADDR
#undef ZADDR
}

// ---------------- host-side GEMM dispatcher ----------------
static inline void gemm_launch(hipStream_t st, int act, bool accum, bool resadd,
                               const float* A, int lda, const float* W, int ldw,
                               const float* bias, float* C, int ldc,
                               const float* res, int M, int N, int K) {
  dim3 g((N + 63) / 64, M / 64), bl(256);
  if (resadd)        hipLaunchKernelGGL((k_gemm<0, false, true>),  g, bl, 0, st, A, lda, W, ldw, bias, C, ldc, res, M, N, K);
  else if (act == 1) hipLaunchKernelGGL((k_gemm<1, false, false>), g, bl, 0, st, A, lda, W, ldw, bias, C, ldc, res, M, N, K);
  else if (act == 2) hipLaunchKernelGGL((k_gemm<2, false, false>), g, bl, 0, st, A, lda, W, ldw, bias, C, ldc, res, M, N, K);
  else if (accum)    hipLaunchKernelGGL((k_gemm<0, true, false>),  g, bl, 0, st, A, lda, W, ldw, bias, C, ldc, res, M, N, K);
  else               hipLaunchKernelGGL((k_gemm<0, false, false>), g, bl, 0, st, A, lda, W, ldw, bias, C, ldc, res, M, N, K);
}

extern "C" void kernel_launch(void* const* d_in, const int* in_sizes, int n_in,
                              void* d_out, int out_size, void* d_ws, size_t ws_size,
                              hipStream_t stream) {
  const float* f_wavlm = (const float*)d_in[0];
  const float* f_sinc  = (const float*)d_in[1];
  const float* ln_w_g  = (const float*)d_in[2];
  const float* ln_w_b  = (const float*)d_in[3];
  const float* ln_s_g  = (const float*)d_in[4];
  const float* ln_s_b  = (const float*)d_in[5];
  const float* W_wp    = (const float*)d_in[6];
  const float* b_wp    = (const float*)d_in[7];
  const float* W_sp    = (const float*)d_in[8];
  const float* b_sp    = (const float*)d_in[9];
  const float* W_fuse  = (const float*)d_in[10];
  const float* b_fuse  = (const float*)d_in[11];
  const float* W_se1   = (const float*)d_in[12];
  const float* W_se2   = (const float*)d_in[13];
  const float* ln_f_g  = (const float*)d_in[14];
  const float* ln_f_b  = (const float*)d_in[15];
  const float* n1_g    = (const float*)d_in[16];
  const float* n1_b    = (const float*)d_in[17];
  const float* n2_g    = (const float*)d_in[18];
  const float* n2_b    = (const float*)d_in[19];
  const float* W_in    = (const float*)d_in[20];
  const float* conv_w  = (const float*)d_in[21];
  const float* conv_b  = (const float*)d_in[22];
  const float* W_xproj = (const float*)d_in[23];
  const float* W_dt    = (const float*)d_in[24];
  const float* b_dt    = (const float*)d_in[25];
  const float* A_log   = (const float*)d_in[26];
  const float* Dp      = (const float*)d_in[27];
  const float* W_out   = (const float*)d_in[28];
  const float* W_ff1   = (const float*)d_in[29];
  const float* b_ff1   = (const float*)d_in[30];
  const float* W_ff2   = (const float*)d_in[31];
  const float* b_ff2   = (const float*)d_in[32];

  float* ws = (float*)d_ws;
  float* pXZ  = ws + OFF_XZ;
  float* pU   = ws + OFF_U;
  float* pDT  = ws + OFF_DT;
  float* pXD  = ws + OFF_XD;
  float* pSP  = ws + OFF_SP;
  float* pSH  = ws + OFF_SH;
  float* pMO  = ws + OFF_MO;
  float* pFW  = ws + OFF_FW;
  float* pFS  = ws + OFF_FS;
  float* pLNS = ws + OFF_LNS;
  float* pFC  = ws + OFF_FC;
  float* pRES = ws + OFF_RES;
  float* pXN  = ws + OFF_XN;
  float* pSE1 = ws + OFF_SE1;
  float* pSE2 = ws + OFF_SE2;

  // 1) LN(f_wavlm) -> XZ scratch ; fw = @ W_wp^T + b -> FW
  hipLaunchKernelGGL(k_layernorm, dim3(4096), dim3(256), 0, stream,
                     f_wavlm, pXZ, ln_w_g, ln_w_b, 1024);
  gemm_launch(stream, 0, false, false, pXZ, 1024, W_wp, 1024, b_wp, pFW, 256,
              nullptr, 4096, 256, 1024);

  // 2) LN(f_sinc) -> LNS ; fs_small -> FS
  hipLaunchKernelGGL(k_layernorm, dim3(2048), dim3(256), 0, stream,
                     f_sinc, pLNS, ln_s_g, ln_s_b, 64);
  gemm_launch(stream, 0, false, false, pLNS, 64, W_sp, 64, b_sp, pFS, 256,
              nullptr, 2048, 256, 64);

  // 3) resize -> DT scratch ; fc = fw@Wf[:,:256]^T + b + fsr@Wf[:,256:]^T -> FC
  hipLaunchKernelGGL(k_resize, dim3(4096), dim3(256), 0, stream, pFS, pDT);
  gemm_launch(stream, 0, false, false, pFW, 256, W_fuse, 512, b_fuse, pFC, 256,
              nullptr, 4096, 256, 256);
  gemm_launch(stream, 0, true, false, pDT, 256, W_fuse + 256, 512, nullptr, pFC, 256,
              nullptr, 4096, 256, 256);

  // 4) SE gate
  hipLaunchKernelGGL(k_se_part, dim3(16, 4), dim3(256), 0, stream, pFC, pSE1);
  hipLaunchKernelGGL(k_se_fin, dim3(4), dim3(256), 0, stream, pSE1, W_se1, W_se2, pSE2);

  // 5) x = LN_f(fc*se) -> RES ; xn = LN_1(x) -> XN
  hipLaunchKernelGGL(k_se_ln, dim3(4096), dim3(256), 0, stream,
                     pFC, pSE2, ln_f_g, ln_f_b, n1_g, n1_b, pRES, pXN);

  // 6) xz = xn @ W_in^T -> XZ (shared by both directions)
  gemm_launch(stream, 0, false, false, pXN, 256, W_in, 256, nullptr, pXZ, 1024,
              nullptr, 4096, 1024, 256);

  // 7) conv+silu both dirs -> U
  hipLaunchKernelGGL(k_conv, dim3(16384), dim3(256), 0, stream, pXZ, conv_w, conv_b, pU);

  // 8) xdbl = U @ W_xproj^T (M=8192) -> XD ; dt = softplus(xdbl[:, :16] @ W_dt^T + b_dt) -> DT
  gemm_launch(stream, 0, false, false, pU, 512, W_xproj, 512, nullptr, pXD, 48,
              nullptr, 8192, 48, 512);
  gemm_launch(stream, 2, false, false, pXD, 48, W_dt, 16, b_dt, pDT, 512,
              nullptr, 8192, 512, 16);

  // 9) chunked scan (both dirs) ; a7 written in place over U
  hipLaunchKernelGGL(k_scan_a, dim3(32, 4, 4), dim3(256), 0, stream,
                     pU, pDT, pXD, A_log, pSP, pSH);
  hipLaunchKernelGGL(k_scan_mid, dim3(32, 4, 2), dim3(256), 0, stream, pSP, pSH);
  hipLaunchKernelGGL(k_scan_b, dim3(32, 4, 4), dim3(256), 0, stream,
                     pU, pDT, pXD, A_log, Dp, pXZ, pSP);

  // 10) out GEMM both dirs (M=8192) -> MO ; m = LN_2(mf+mb) -> FC
  gemm_launch(stream, 0, false, false, pU, 512, W_out, 512, nullptr, pMO, 256,
              nullptr, 8192, 256, 512);
  hipLaunchKernelGGL(k_layernorm2, dim3(4096), dim3(256), 0, stream, pMO, pFC, n2_g, n2_b);

  // 11) ff1 = gelu(m @ W_ff1^T + b) -> DT ; out = ff1 @ W_ff2^T + b + res
  gemm_launch(stream, 1, false, false, pFC, 256, W_ff1, 256, b_ff1, pDT, 1024,
              nullptr, 4096, 1024, 256);
  gemm_launch(stream, 0, false, true, pDT, 1024, W_ff2, 1024, b_ff2,
              (float*)d_out, 256, pRES, 4096, 256, 1024);
}

// Round 4
// 430.010 us; speedup vs baseline: 2.8465x; 1.6362x over previous
//
#include <hip/hip_runtime.h>
#include <math.h>

#define DEV_INLINE __device__ __forceinline__

typedef __attribute__((ext_vector_type(8))) short bf16x8;
typedef __attribute__((ext_vector_type(4))) float f32x4;

struct US4 { unsigned short x, y, z, w; };

DEV_INLINE unsigned short f2bf(float f) {
  union { float f; unsigned u; } v; v.f = f;
  unsigned r = v.u + 0x7fff + ((v.u >> 16) & 1);
  return (unsigned short)(r >> 16);
}
DEV_INLINE float bf2f(unsigned short h) {
  union { unsigned u; float f; } v; v.u = ((unsigned)h) << 16;
  return v.f;
}

// ---------------- workspace layout (float offsets) ----------------
static constexpr size_t OFF_XZ   = 0;          // 4M floats: early bf16 scratch, then xz f32
static constexpr size_t SUB_LNW  = 0;          // bf16 4096x1024 (2M fl)
static constexpr size_t SUB_LNS  = 2097152;    // bf16 2048x64   (64K fl)
static constexpr size_t SUB_CAT  = 2162688;    // bf16 4096x512  (1M fl)
static constexpr size_t SUB_FSB  = 3211264;    // bf16 2048x256  (256K fl)
static constexpr size_t OFF_U    = 4194304;    // 4M fl: conv out f32 both dirs
static constexpr size_t OFF_DT   = 8388608;    // 4M fl: dt f32; later mb+ff1b
static constexpr size_t SUB_MB   = 8388608;    // bf16 4096x256 (512K fl)
static constexpr size_t SUB_FF1B = 8912896;    // bf16 4096x1024 (2M fl)
static constexpr size_t OFF_XD   = 12582912;   // 393,216 fl: xdbl f32 (8192x48)
static constexpr size_t OFF_SP   = 12976128;   // 2M fl: scan products; later MO f32
static constexpr size_t OFF_SH   = 15073280;   // 2M fl
static constexpr size_t OFF_FC   = 17170432;   // 1M fl f32
static constexpr size_t OFF_RES  = 18219008;   // 1M fl f32
static constexpr size_t OFF_XNB  = 19267584;   // bf16 4096x256 (512K fl)
static constexpr size_t OFF_UB   = 19791872;   // bf16 8192x512 (2M fl)
static constexpr size_t OFF_WB   = 21889024;   // bf16 weights (675,840 fl)
static constexpr size_t OFF_SE1  = 22564864;   // 16K fl
static constexpr size_t OFF_SE2  = 22581248;   // 1K fl

// bf16 weight sub-offsets (ushort units) inside WB
static constexpr size_t WB_WP    = 0;          // 256x1024
static constexpr size_t WB_SP    = 262144;     // 256x64
static constexpr size_t WB_FUSE  = 278528;     // 256x512
static constexpr size_t WB_IN    = 409600;     // 1024x256
static constexpr size_t WB_XPROJ = 671744;     // 48x512
static constexpr size_t WB_OUT   = 696320;     // 256x512
static constexpr size_t WB_FF1   = 827392;     // 1024x256
static constexpr size_t WB_FF2   = 1089536;    // 256x1024

// ---------------- weight f32 -> bf16 converter (all 8 GEMM weights) --------
__global__ void k_w2bf(const float* __restrict__ w0, const float* __restrict__ w1,
                       const float* __restrict__ w2, const float* __restrict__ w3,
                       const float* __restrict__ w4, const float* __restrict__ w5,
                       const float* __restrict__ w6, const float* __restrict__ w7,
                       unsigned short* __restrict__ dst) {
  int i = blockIdx.x * 256 + threadIdx.x;  // float4 index, total 337,920
  const float* s; size_t dbase; int rel;
  if      (i <  65536) { s = w0; rel = i;          dbase = WB_WP; }
  else if (i <  69632) { s = w1; rel = i -  65536; dbase = WB_SP; }
  else if (i < 102400) { s = w2; rel = i -  69632; dbase = WB_FUSE; }
  else if (i < 167936) { s = w3; rel = i - 102400; dbase = WB_IN; }
  else if (i < 174080) { s = w4; rel = i - 167936; dbase = WB_XPROJ; }
  else if (i < 206848) { s = w5; rel = i - 174080; dbase = WB_OUT; }
  else if (i < 272384) { s = w6; rel = i - 206848; dbase = WB_FF1; }
  else                 { s = w7; rel = i - 272384; dbase = WB_FF2; }
  float4 v = reinterpret_cast<const float4*>(s)[rel];
  US4 o = { f2bf(v.x), f2bf(v.y), f2bf(v.z), f2bf(v.w) };
  reinterpret_cast<US4*>(dst + dbase)[rel] = o;
}

// ---------------- block-wide sum, blockDim == 256 ----------------
DEV_INLINE float blockSum256(float v) {
  __shared__ float sh[4];
  int lane = threadIdx.x & 63;
  int w    = threadIdx.x >> 6;
#pragma unroll
  for (int o = 32; o; o >>= 1) v += __shfl_down(v, o, 64);
  __syncthreads();
  if (lane == 0) sh[w] = v;
  __syncthreads();
  return sh[0] + sh[1] + sh[2] + sh[3];
}

// ---------------- row LayerNorm (L <= 1024), bf16 out ----------------
__global__ void k_layernorm(const float* __restrict__ in, unsigned short* __restrict__ out,
                            const float* __restrict__ g, const float* __restrict__ b,
                            int L) {
  __shared__ float row[1024];
  size_t rid = blockIdx.x;
  const float* x = in + rid * (size_t)L;
  float s = 0.f;
  for (int i = threadIdx.x; i < L; i += 256) { float v = x[i]; row[i] = v; s += v; }
  float mean = blockSum256(s) / (float)L;
  float vs = 0.f;
  for (int i = threadIdx.x; i < L; i += 256) { float d = row[i] - mean; vs += d * d; }
  float var = blockSum256(vs) / (float)L;
  float rstd = rsqrtf(var + 1e-5f);
  for (int i = threadIdx.x; i < L; i += 256)
    out[rid * (size_t)L + i] = f2bf((row[i] - mean) * rstd * g[i] + b[i]);
}

// ---------------- LN over sum of two 256-wide rows (mf+mb), bf16 out --------
__global__ void k_layernorm2(const float* __restrict__ mo, unsigned short* __restrict__ out,
                             const float* __restrict__ g, const float* __restrict__ b) {
  size_t rid = blockIdx.x;  // 0..4095
  int e = threadIdx.x;
  float v = mo[rid * 256 + e] + mo[(rid + 4096) * 256 + e];
  float m1 = blockSum256(v) * (1.f / 256.f);
  float d = v - m1;
  float var = blockSum256(d * d) * (1.f / 256.f);
  out[rid * 256 + e] = f2bf(d * rsqrtf(var + 1e-5f) * g[e] + b[e]);
}

// ---------------- bf16 MFMA GEMM: C[M,N] = epi(A[M,K] @ W[N,K]^T) -----------
// block = 128 thr = 2 waves; wave computes 16m x 64n; grid ((N+63)/64, M/32).
// A,W bf16 row-major. ACT: 0 none, 1 exact gelu. OUTBF: write bf16 else f32.
template <int ACT, bool RESADD, bool OUTBF>
__global__ __launch_bounds__(128) void k_mgemm(
    const short* __restrict__ A, int lda,
    const short* __restrict__ W, int ldw,
    const float* __restrict__ bias,
    float* __restrict__ Cf, unsigned short* __restrict__ Cb, int ldc,
    const float* __restrict__ res,
    int M, int N, int K) {
  int l = threadIdx.x & 63, w = threadIdx.x >> 6;
  int bm = blockIdx.y << 5, bn = blockIdx.x << 6;
  int r = l & 15, ko = (l >> 4) << 3;
  const short* Ap = A + (size_t)(bm + (w << 4) + r) * lda + ko;
  const short* Wp = W + (size_t)(bn + r) * ldw + ko;
  f32x4 acc[4] = {{0.f,0.f,0.f,0.f},{0.f,0.f,0.f,0.f},{0.f,0.f,0.f,0.f},{0.f,0.f,0.f,0.f}};
#pragma unroll 2
  for (int k0 = 0; k0 < K; k0 += 32) {
    bf16x8 av = *reinterpret_cast<const bf16x8*>(Ap + k0);
#pragma unroll
    for (int t = 0; t < 4; t++) {
      if (bn + t * 16 < N) {
        bf16x8 bv = *reinterpret_cast<const bf16x8*>(Wp + (size_t)(t * 16) * ldw + k0);
        acc[t] = __builtin_amdgcn_mfma_f32_16x16x32_bf16(av, bv, acc[t], 0, 0, 0);
      }
    }
  }
#pragma unroll
  for (int t = 0; t < 4; t++) {
    if (bn + t * 16 < N) {
      int n = bn + t * 16 + r;
      float bb = bias ? bias[n] : 0.f;
#pragma unroll
      for (int q = 0; q < 4; q++) {
        int m = bm + (w << 4) + ((l >> 4) << 2) + q;
        float v = acc[t][q] + bb;
        if (ACT == 1) v = 0.5f * v * (1.f + erff(v * 0.70710678118f));
        size_t oi = (size_t)m * ldc + n;
        if (OUTBF) {
          Cb[oi] = f2bf(v);
        } else {
          if (RESADD) v += res[oi];
          Cf[oi] = v;
        }
      }
    }
  }
}

// ---------------- f32 GEMM (kept for the K=16 dt projection) ----------------
template <int ACT>
__global__ __launch_bounds__(256) void k_gemm(
    const float* __restrict__ A, int lda,
    const float* __restrict__ W, int ldw,
    const float* __restrict__ bias,
    float* __restrict__ C, int ldc,
    int M, int N, int K) {
  __shared__ float As[16][68];
  __shared__ float Ws[16][68];
  int tid = threadIdx.x;
  int bm = blockIdx.y << 6, bn = blockIdx.x << 6;
  int tx = tid & 15, ty = tid >> 4;
  int m0 = ty << 2, n0 = tx << 2;
  float acc[4][4] = {};
  int kk = tid & 15, rr = tid >> 4;
  for (int k0 = 0; k0 < K; k0 += 16) {
#pragma unroll
    for (int j = 0; j < 4; j++) {
      int m = (rr << 2) + j;
      As[kk][m] = A[(size_t)(bm + m) * lda + k0 + kk];
      int n = (rr << 2) + j;
      Ws[kk][n] = (bn + n < N) ? W[(size_t)(bn + n) * ldw + k0 + kk] : 0.f;
    }
    __syncthreads();
#pragma unroll
    for (int q = 0; q < 16; q++) {
      float4 av = *reinterpret_cast<const float4*>(&As[q][m0]);
      float4 bv = *reinterpret_cast<const float4*>(&Ws[q][n0]);
      float a[4] = {av.x, av.y, av.z, av.w};
      float b[4] = {bv.x, bv.y, bv.z, bv.w};
#pragma unroll
      for (int i = 0; i < 4; i++)
#pragma unroll
        for (int j = 0; j < 4; j++) acc[i][j] += a[i] * b[j];
    }
    __syncthreads();
  }
#pragma unroll
  for (int i = 0; i < 4; i++) {
#pragma unroll
    for (int j = 0; j < 4; j++) {
      int row = bm + m0 + i, col = bn + n0 + j;
      if (col < N) {
        float v = acc[i][j];
        if (bias) v += bias[col];
        if (ACT == 2) v = (v > 20.f) ? v : log1pf(expf(v));
        C[(size_t)row * ldc + col] = v;
      }
    }
  }
}

// ---------------- linear resize T 512 -> 1024 (bf16 in/out into CAT) --------
__global__ void k_resize(const unsigned short* __restrict__ fs,
                         unsigned short* __restrict__ cat) {
  int idx = blockIdx.x * 256 + threadIdx.x;
  int e = idx & 255, t = (idx >> 8) & 1023, b = idx >> 18;
  int j = t >> 1;
  int j0, j1; float w0, w1;
  if ((t & 1) == 0) { j0 = j > 0 ? j - 1 : 0; j1 = j; w0 = 0.25f; w1 = 0.75f; }
  else              { j0 = j; j1 = j < 511 ? j + 1 : 511; w0 = 0.75f; w1 = 0.25f; }
  float v = w0 * bf2f(fs[((size_t)(b << 9) + j0) * 256 + e]) +
            w1 * bf2f(fs[((size_t)(b << 9) + j1) * 256 + e]);
  cat[((size_t)(b << 10) + t) * 512 + 256 + e] = f2bf(v);
}

// ---------------- SE ----------------
__global__ void k_se_part(const float* __restrict__ fc, float* __restrict__ part) {
  int b = blockIdx.y, chunk = blockIdx.x, e = threadIdx.x;
  float s = 0.f;
  for (int j = 0; j < 64; j++) {
    int t = chunk * 64 + j;
    s += fc[((size_t)(b << 10) + t) * 256 + e];
  }
  part[(size_t)(b * 16 + chunk) * 256 + e] = s;
}

__global__ void k_se_fin(const float* __restrict__ part, const float* __restrict__ W1,
                         const float* __restrict__ W2, float* __restrict__ se) {
  int b = blockIdx.x, tid = threadIdx.x;
  __shared__ float mean[256];
  __shared__ float hid[16];
  float s = 0.f;
  for (int c = 0; c < 16; c++) s += part[(size_t)(b * 16 + c) * 256 + tid];
  mean[tid] = s * (1.f / 1024.f);
  __syncthreads();
  int o = tid >> 4, l = tid & 15;
  float p = 0.f;
  for (int e = l; e < 256; e += 16) p += mean[e] * W1[o * 256 + e];
  p += __shfl_xor(p, 1, 64); p += __shfl_xor(p, 2, 64);
  p += __shfl_xor(p, 4, 64); p += __shfl_xor(p, 8, 64);
  if (l == 0) hid[o] = fmaxf(p, 0.f);
  __syncthreads();
  float s2 = 0.f;
  for (int o2 = 0; o2 < 16; o2++) s2 += hid[o2] * W2[tid * 16 + o2];
  se[b * 256 + tid] = 1.f / (1.f + expf(-s2));
}

// ---------------- fused SE-scale + LN_f + LN_1 ----------------
__global__ void k_se_ln(const float* __restrict__ fc, const float* __restrict__ se,
                        const float* __restrict__ gf, const float* __restrict__ bf,
                        const float* __restrict__ g1, const float* __restrict__ b1,
                        float* __restrict__ xout, unsigned short* __restrict__ xnb) {
  size_t rid = blockIdx.x;
  int b = (int)(rid >> 10);
  int e = threadIdx.x;
  float v = fc[rid * 256 + e] * se[b * 256 + e];
  float m1 = blockSum256(v) * (1.f / 256.f);
  float d = v - m1;
  float var = blockSum256(d * d) * (1.f / 256.f);
  float x = d * rsqrtf(var + 1e-5f) * gf[e] + bf[e];
  xout[rid * 256 + e] = x;
  float m2 = blockSum256(x) * (1.f / 256.f);
  float d2 = x - m2;
  float v2 = blockSum256(d2 * d2) * (1.f / 256.f);
  xnb[rid * 256 + e] = f2bf(d2 * rsqrtf(v2 + 1e-5f) * g1[e] + b1[e]);
}

// ---------------- depthwise conv + silu, both dirs; f32 + bf16 out ----------
__global__ void k_conv(const float* __restrict__ xz, const float* __restrict__ cw,
                       const float* __restrict__ cb, float* __restrict__ out,
                       unsigned short* __restrict__ outb) {
  size_t idx = (size_t)blockIdx.x * 256 + threadIdx.x;  // (dir,b,t,d)
  int d = idx & 511, t = ((int)(idx >> 9)) & 1023, b = ((int)(idx >> 19)) & 3;
  int dir = (int)(idx >> 21);
  float acc = cb[d];
#pragma unroll
  for (int k = 0; k < 4; k++) {
    int tt = dir ? (t + 3 - k) : (t + k - 3);
    if (tt >= 0 && tt < 1024)
      acc += xz[(((size_t)(b << 10) + tt) << 10) + d] * cw[(d << 2) + k];
  }
  float v = acc / (1.f + expf(-acc));  // silu
  out[idx] = v;
  outb[idx] = f2bf(v);
}

// ---------------- selective scan (chunked parallel, h in registers) ---------
__global__ __launch_bounds__(256) void k_scan_a(
    const float* __restrict__ u, const float* __restrict__ dtb,
    const float* __restrict__ xdbl, const float* __restrict__ A_log,
    float* __restrict__ SP, float* __restrict__ SH) {
  int chunk = blockIdx.x, b = blockIdx.y;
  int dir = blockIdx.z >> 1, dhalf = blockIdx.z & 1;
  int d = (dhalf << 8) + threadIdx.x;
  __shared__ float Bs[32][16];
  for (int i = threadIdx.x; i < 512; i += 256) {
    int j = i >> 4, n = i & 15;
    int s = (chunk << 5) + j;
    int t = dir ? (1023 - s) : s;
    Bs[j][n] = xdbl[((size_t)((dir * 4 + b) * 1024 + t)) * 48 + 16 + n];
  }
  float a[16], h[16], P[16];
#pragma unroll
  for (int n = 0; n < 16; n++) {
    a[n] = -__expf(A_log[d * 16 + n]);
    h[n] = 0.f; P[n] = 1.f;
  }
  __syncthreads();
  size_t base = (size_t)(dir * 4 + b) * 1024;
  int s0 = chunk << 5;
#define ADDR(j) ((base + (dir ? (1023 - (s0 + (j))) : (s0 + (j)))) * 512 + d)
  float dt_n = dtb[ADDR(0)], u_n = u[ADDR(0)];
#pragma unroll 4
  for (int j = 0; j < 32; j++) {
    float dtv = dt_n, uv = u_n;
    if (j < 31) { dt_n = dtb[ADDR(j + 1)]; u_n = u[ADDR(j + 1)]; }
    float c1 = dtv * uv;
    const float4* Bp = reinterpret_cast<const float4*>(&Bs[j][0]);
    float4 b0 = Bp[0], b1 = Bp[1], b2 = Bp[2], b3 = Bp[3];
    float Bv[16] = {b0.x, b0.y, b0.z, b0.w, b1.x, b1.y, b1.z, b1.w,
                    b2.x, b2.y, b2.z, b2.w, b3.x, b3.y, b3.z, b3.w};
#pragma unroll
    for (int n = 0; n < 16; n++) {
      float dA = __expf(dtv * a[n]);
      h[n] = dA * h[n] + c1 * Bv[n];
      P[n] *= dA;
    }
  }
  size_t o = ((size_t)((dir * 4 + b) * 32 + chunk) * 512 + d) * 16;
#pragma unroll
  for (int n = 0; n < 16; n++) { SP[o + n] = P[n]; SH[o + n] = h[n]; }
#undef ADDR
}

__global__ __launch_bounds__(256) void k_scan_mid(float* __restrict__ SP,
                                                  const float* __restrict__ SH) {
  int dir = blockIdx.z, b = blockIdx.y;
  int d = (blockIdx.x << 4) + (threadIdx.x >> 4);
  int n = threadIdx.x & 15;
  const size_t cs = 512 * 16;
  size_t base = ((size_t)(dir * 4 + b) * 32) * cs + (size_t)d * 16 + n;
  float H = 0.f;
  float Pv = SP[base], hE = SH[base];
  for (int c = 0; c < 32; c++) {
    float Pc = Pv, hc = hE;
    if (c < 31) { Pv = SP[base + (c + 1) * cs]; hE = SH[base + (c + 1) * cs]; }
    SP[base + (size_t)c * cs] = H;
    H = Pc * H + hc;
  }
}

// Phase B: re-run scan with start state; y = C.h + u*D; silu(z) gate; bf16 out
__global__ __launch_bounds__(256) void k_scan_b(
    const float* __restrict__ u, const float* __restrict__ dtb,
    const float* __restrict__ xdbl, const float* __restrict__ A_log,
    const float* __restrict__ Dp, const float* __restrict__ xz,
    const float* __restrict__ SP, unsigned short* __restrict__ ub) {
  int chunk = blockIdx.x, b = blockIdx.y;
  int dir = blockIdx.z >> 1, dhalf = blockIdx.z & 1;
  int d = (dhalf << 8) + threadIdx.x;
  __shared__ float Bs[32][16];
  __shared__ float Cs[32][16];
  for (int i = threadIdx.x; i < 512; i += 256) {
    int j = i >> 4, n = i & 15;
    int s = (chunk << 5) + j;
    int t = dir ? (1023 - s) : s;
    size_t row = ((size_t)((dir * 4 + b) * 1024 + t)) * 48;
    Bs[j][n] = xdbl[row + 16 + n];
    Cs[j][n] = xdbl[row + 32 + n];
  }
  float a[16], h[16];
  size_t so = ((size_t)((dir * 4 + b) * 32 + chunk) * 512 + d) * 16;
#pragma unroll
  for (int n = 0; n < 16; n++) {
    a[n] = -__expf(A_log[d * 16 + n]);
    h[n] = SP[so + n];
  }
  float Dval = Dp[d];
  __syncthreads();
  size_t base = (size_t)(dir * 4 + b) * 1024;
  size_t zbase = (size_t)b << 10;
  int s0 = chunk << 5;
#define ADDR(j) ((base + (dir ? (1023 - (s0 + (j))) : (s0 + (j)))) * 512 + d)
#define ZADDR(j) ((((zbase + (dir ? (1023 - (s0 + (j))) : (s0 + (j)))) << 10)) + 512 + d)
  float dt_n = dtb[ADDR(0)], u_n = u[ADDR(0)], z_n = xz[ZADDR(0)];
#pragma unroll 4
  for (int j = 0; j < 32; j++) {
    float dtv = dt_n, uv = u_n, zv = z_n;
    if (j < 31) { dt_n = dtb[ADDR(j + 1)]; u_n = u[ADDR(j + 1)]; z_n = xz[ZADDR(j + 1)]; }
    float c1 = dtv * uv;
    const float4* Bp = reinterpret_cast<const float4*>(&Bs[j][0]);
    const float4* Cp = reinterpret_cast<const float4*>(&Cs[j][0]);
    float4 b0 = Bp[0], b1 = Bp[1], b2 = Bp[2], b3 = Bp[3];
    float4 c0 = Cp[0], c4 = Cp[1], c8 = Cp[2], cc = Cp[3];
    float Bv[16] = {b0.x, b0.y, b0.z, b0.w, b1.x, b1.y, b1.z, b1.w,
                    b2.x, b2.y, b2.z, b2.w, b3.x, b3.y, b3.z, b3.w};
    float Cv[16] = {c0.x, c0.y, c0.z, c0.w, c4.x, c4.y, c4.z, c4.w,
                    c8.x, c8.y, c8.z, c8.w, cc.x, cc.y, cc.z, cc.w};
    float y0 = 0.f, y1 = 0.f, y2 = 0.f, y3 = 0.f;
#pragma unroll
    for (int n = 0; n < 16; n++) {
      float dA = __expf(dtv * a[n]);
      h[n] = dA * h[n] + c1 * Bv[n];
      float p = h[n] * Cv[n];
      if ((n & 3) == 0) y0 += p; else if ((n & 3) == 1) y1 += p;
      else if ((n & 3) == 2) y2 += p; else y3 += p;
    }
    float y = (y0 + y1) + (y2 + y3) + uv * Dval;
    float sig = 1.f / (1.f + expf(-zv));
    ub[ADDR(j)] = f2bf(y * zv * sig);
  }
#undef ADDR
#undef ZADDR
}

// ---------------- host-side MFMA GEMM dispatcher ----------------
static inline void mgemm(hipStream_t st, int act, bool resadd, bool outbf,
                         const void* A, int lda, const void* W, int ldw,
                         const float* bias, void* Cf, void* Cb, int ldc,
                         const float* res, int M, int N, int K) {
  dim3 g((N + 63) / 64, M / 32), bl(128);
  const short* a = (const short*)A;
  const short* w = (const short*)W;
  float* cf = (float*)Cf;
  unsigned short* cb = (unsigned short*)Cb;
  if (outbf) {
    if (act == 1) hipLaunchKernelGGL((k_mgemm<1, false, true>), g, bl, 0, st, a, lda, w, ldw, bias, cf, cb, ldc, res, M, N, K);
    else          hipLaunchKernelGGL((k_mgemm<0, false, true>), g, bl, 0, st, a, lda, w, ldw, bias, cf, cb, ldc, res, M, N, K);
  } else {
    if (resadd)   hipLaunchKernelGGL((k_mgemm<0, true, false>), g, bl, 0, st, a, lda, w, ldw, bias, cf, cb, ldc, res, M, N, K);
    else          hipLaunchKernelGGL((k_mgemm<0, false, false>), g, bl, 0, st, a, lda, w, ldw, bias, cf, cb, ldc, res, M, N, K);
  }
}

extern "C" void kernel_launch(void* const* d_in, const int* in_sizes, int n_in,
                              void* d_out, int out_size, void* d_ws, size_t ws_size,
                              hipStream_t stream) {
  const float* f_wavlm = (const float*)d_in[0];
  const float* f_sinc  = (const float*)d_in[1];
  const float* ln_w_g  = (const float*)d_in[2];
  const float* ln_w_b  = (const float*)d_in[3];
  const float* ln_s_g  = (const float*)d_in[4];
  const float* ln_s_b  = (const float*)d_in[5];
  const float* W_wp    = (const float*)d_in[6];
  const float* b_wp    = (const float*)d_in[7];
  const float* W_sp    = (const float*)d_in[8];
  const float* b_sp    = (const float*)d_in[9];
  const float* W_fuse  = (const float*)d_in[10];
  const float* b_fuse  = (const float*)d_in[11];
  const float* W_se1   = (const float*)d_in[12];
  const float* W_se2   = (const float*)d_in[13];
  const float* ln_f_g  = (const float*)d_in[14];
  const float* ln_f_b  = (const float*)d_in[15];
  const float* n1_g    = (const float*)d_in[16];
  const float* n1_b    = (const float*)d_in[17];
  const float* n2_g    = (const float*)d_in[18];
  const float* n2_b    = (const float*)d_in[19];
  const float* W_in    = (const float*)d_in[20];
  const float* conv_w  = (const float*)d_in[21];
  const float* conv_b  = (const float*)d_in[22];
  const float* W_xproj = (const float*)d_in[23];
  const float* W_dt    = (const float*)d_in[24];
  const float* b_dt    = (const float*)d_in[25];
  const float* A_log   = (const float*)d_in[26];
  const float* Dp      = (const float*)d_in[27];
  const float* W_out   = (const float*)d_in[28];
  const float* W_ff1   = (const float*)d_in[29];
  const float* b_ff1   = (const float*)d_in[30];
  const float* W_ff2   = (const float*)d_in[31];
  const float* b_ff2   = (const float*)d_in[32];

  float* ws = (float*)d_ws;
  float* pXZ  = ws + OFF_XZ;
  unsigned short* pLNW = (unsigned short*)(ws + SUB_LNW);
  unsigned short* pLNS = (unsigned short*)(ws + SUB_LNS);
  unsigned short* pCAT = (unsigned short*)(ws + SUB_CAT);
  unsigned short* pFSB = (unsigned short*)(ws + SUB_FSB);
  float* pU   = ws + OFF_U;
  float* pDT  = ws + OFF_DT;
  unsigned short* pMB   = (unsigned short*)(ws + SUB_MB);
  unsigned short* pFF1B = (unsigned short*)(ws + SUB_FF1B);
  float* pXD  = ws + OFF_XD;
  float* pSP  = ws + OFF_SP;
  float* pMO  = ws + OFF_SP;   // reuse after scan
  float* pSH  = ws + OFF_SH;
  float* pFC  = ws + OFF_FC;
  float* pRES = ws + OFF_RES;
  unsigned short* pXNB = (unsigned short*)(ws + OFF_XNB);
  unsigned short* pUB  = (unsigned short*)(ws + OFF_UB);
  unsigned short* pWB  = (unsigned short*)(ws + OFF_WB);
  float* pSE1 = ws + OFF_SE1;
  float* pSE2 = ws + OFF_SE2;

  // 0) convert all GEMM weights to bf16
  hipLaunchKernelGGL(k_w2bf, dim3(1320), dim3(256), 0, stream,
                     W_wp, W_sp, W_fuse, W_in, W_xproj, W_out, W_ff1, W_ff2, pWB);

  // 1) LN(f_wavlm) -> LNW bf16 ; fw = @ W_wp^T + b -> CAT cols 0-255 (bf16)
  hipLaunchKernelGGL(k_layernorm, dim3(4096), dim3(256), 0, stream,
                     f_wavlm, pLNW, ln_w_g, ln_w_b, 1024);
  mgemm(stream, 0, false, true, pLNW, 1024, pWB + WB_WP, 1024, b_wp,
        nullptr, pCAT, 512, nullptr, 4096, 256, 1024);

  // 2) LN(f_sinc) -> LNS bf16 ; fs_small -> FSB bf16
  hipLaunchKernelGGL(k_layernorm, dim3(2048), dim3(256), 0, stream,
                     f_sinc, pLNS, ln_s_g, ln_s_b, 64);
  mgemm(stream, 0, false, true, pLNS, 64, pWB + WB_SP, 64, b_sp,
        nullptr, pFSB, 256, nullptr, 2048, 256, 64);

  // 3) resize -> CAT cols 256-511 ; fc = CAT @ W_fuse^T + b (K=512) -> FC f32
  hipLaunchKernelGGL(k_resize, dim3(4096), dim3(256), 0, stream, pFSB, pCAT);
  mgemm(stream, 0, false, false, pCAT, 512, pWB + WB_FUSE, 512, b_fuse,
        pFC, nullptr, 256, nullptr, 4096, 256, 512);

  // 4) SE gate
  hipLaunchKernelGGL(k_se_part, dim3(16, 4), dim3(256), 0, stream, pFC, pSE1);
  hipLaunchKernelGGL(k_se_fin, dim3(4), dim3(256), 0, stream, pSE1, W_se1, W_se2, pSE2);

  // 5) x = LN_f(fc*se) -> RES f32 ; xn = LN_1(x) -> XNB bf16
  hipLaunchKernelGGL(k_se_ln, dim3(4096), dim3(256), 0, stream,
                     pFC, pSE2, ln_f_g, ln_f_b, n1_g, n1_b, pRES, pXNB);

  // 6) xz = xn @ W_in^T -> XZ f32 (overwrites early bf16 scratch)
  mgemm(stream, 0, false, false, pXNB, 256, pWB + WB_IN, 256, nullptr,
        pXZ, nullptr, 1024, nullptr, 4096, 1024, 256);

  // 7) conv+silu both dirs -> U f32 + UB bf16
  hipLaunchKernelGGL(k_conv, dim3(16384), dim3(256), 0, stream,
                     pXZ, conv_w, conv_b, pU, pUB);

  // 8) xdbl = U @ W_xproj^T (M=8192, N=48) -> XD f32 ;
  //    dt = softplus(xdbl[:, :16] @ W_dt^T + b_dt) -> DT f32 (f32 GEMM, K=16)
  mgemm(stream, 0, false, false, pUB, 512, pWB + WB_XPROJ, 512, nullptr,
        pXD, nullptr, 48, nullptr, 8192, 48, 512);
  hipLaunchKernelGGL((k_gemm<2>), dim3(8, 128), dim3(256), 0, stream,
                     pXD, 48, W_dt, 16, b_dt, pDT, 512, 8192, 512, 16);

  // 9) chunked scan (both dirs) ; a7 -> UB bf16 (overwrites conv bf16)
  hipLaunchKernelGGL(k_scan_a, dim3(32, 4, 4), dim3(256), 0, stream,
                     pU, pDT, pXD, A_log, pSP, pSH);
  hipLaunchKernelGGL(k_scan_mid, dim3(32, 4, 2), dim3(256), 0, stream, pSP, pSH);
  hipLaunchKernelGGL(k_scan_b, dim3(32, 4, 4), dim3(256), 0, stream,
                     pU, pDT, pXD, A_log, Dp, pXZ, pSP, pUB);

  // 10) out GEMM both dirs -> MO f32 ; m = LN_2(mf+mb) -> MB bf16
  mgemm(stream, 0, false, false, pUB, 512, pWB + WB_OUT, 512, nullptr,
        pMO, nullptr, 256, nullptr, 8192, 256, 512);
  hipLaunchKernelGGL(k_layernorm2, dim3(4096), dim3(256), 0, stream, pMO, pMB, n2_g, n2_b);

  // 11) ff1 = gelu(m @ W_ff1^T + b) -> FF1B bf16 ; out = ff1 @ W_ff2^T + b + res
  mgemm(stream, 1, false, true, pMB, 256, pWB + WB_FF1, 256, b_ff1,
        nullptr, pFF1B, 1024, nullptr, 4096, 1024, 256);
  mgemm(stream, 0, true, false, pFF1B, 1024, pWB + WB_FF2, 1024, b_ff2,
        d_out, nullptr, 256, pRES, 4096, 256, 1024);
}

// Round 5
// 401.977 us; speedup vs baseline: 3.0450x; 1.0697x over previous
//
#include <hip/hip_runtime.h>
#include <math.h>

#define DEV_INLINE __device__ __forceinline__

typedef __attribute__((ext_vector_type(8))) short bf16x8;
typedef __attribute__((ext_vector_type(4))) float f32x4;

struct US4 { unsigned short x, y, z, w; };

DEV_INLINE unsigned short f2bf(float f) {
  union { float f; unsigned u; } v; v.f = f;
  unsigned r = v.u + 0x7fff + ((v.u >> 16) & 1);
  return (unsigned short)(r >> 16);
}
DEV_INLINE float bf2f(unsigned short h) {
  union { unsigned u; float f; } v; v.u = ((unsigned)h) << 16;
  return v.f;
}
DEV_INLINE float softplusf(float x) {
  return x > 20.f ? x : __logf(1.f + __expf(x));
}

// ---------------- workspace layout (float offsets) ----------------
static constexpr size_t OFF_XZ   = 0;          // 4M fl: early bf16 scratch, then xz f32
static constexpr size_t SUB_LNW  = 0;          // bf16 4096x1024 (2M fl)
static constexpr size_t SUB_LNS  = 2097152;    // bf16 2048x64   (64K fl)
static constexpr size_t SUB_CAT  = 2162688;    // bf16 4096x512  (1M fl)
static constexpr size_t SUB_FSB  = 3211264;    // bf16 2048x256  (256K fl)
static constexpr size_t OFF_UB   = 4194304;    // bf16 8192x512  (2M fl): conv out -> a7
static constexpr size_t OFF_XD   = 6291456;    // 393,216 fl: xdbl f32 (8192x48)
static constexpr size_t OFF_SP   = 6684672;    // 2M fl: scan products/starts; later MO f32
static constexpr size_t OFF_SH   = 8781824;    // 2M fl
static constexpr size_t OFF_FC   = 10878976;   // 1M fl
static constexpr size_t OFF_RES  = 11927552;   // 1M fl
static constexpr size_t OFF_XNB  = 12976128;   // bf16 4096x256 (512K fl)
static constexpr size_t OFF_MB   = 13500416;   // bf16 4096x256 (512K fl)
static constexpr size_t OFF_FF1B = 14024704;   // bf16 4096x1024 (2M fl)
static constexpr size_t OFF_WB   = 16121856;   // bf16 weights (675,840 fl)
static constexpr size_t OFF_SE1  = 16797696;   // 16K fl
static constexpr size_t OFF_SE2  = 16814080;   // 1K fl

// bf16 weight sub-offsets (ushort units) inside WB
static constexpr size_t WB_WP    = 0;          // 256x1024
static constexpr size_t WB_SP    = 262144;     // 256x64
static constexpr size_t WB_FUSE  = 278528;     // 256x512
static constexpr size_t WB_IN    = 409600;     // 1024x256
static constexpr size_t WB_XPROJ = 671744;     // 48x512
static constexpr size_t WB_OUT   = 696320;     // 256x512
static constexpr size_t WB_FF1   = 827392;     // 1024x256
static constexpr size_t WB_FF2   = 1089536;    // 256x1024

// ---------------- weight f32 -> bf16 converter ----------------
__global__ void k_w2bf(const float* __restrict__ w0, const float* __restrict__ w1,
                       const float* __restrict__ w2, const float* __restrict__ w3,
                       const float* __restrict__ w4, const float* __restrict__ w5,
                       const float* __restrict__ w6, const float* __restrict__ w7,
                       unsigned short* __restrict__ dst) {
  int i = blockIdx.x * 256 + threadIdx.x;  // float4 index, total 337,920
  const float* s; size_t dbase; int rel;
  if      (i <  65536) { s = w0; rel = i;          dbase = WB_WP; }
  else if (i <  69632) { s = w1; rel = i -  65536; dbase = WB_SP; }
  else if (i < 102400) { s = w2; rel = i -  69632; dbase = WB_FUSE; }
  else if (i < 167936) { s = w3; rel = i - 102400; dbase = WB_IN; }
  else if (i < 174080) { s = w4; rel = i - 167936; dbase = WB_XPROJ; }
  else if (i < 206848) { s = w5; rel = i - 174080; dbase = WB_OUT; }
  else if (i < 272384) { s = w6; rel = i - 206848; dbase = WB_FF1; }
  else                 { s = w7; rel = i - 272384; dbase = WB_FF2; }
  float4 v = reinterpret_cast<const float4*>(s)[rel];
  US4 o = { f2bf(v.x), f2bf(v.y), f2bf(v.z), f2bf(v.w) };
  reinterpret_cast<US4*>(dst + dbase)[rel] = o;
}

// ---------------- block-wide sum, blockDim == 256 ----------------
DEV_INLINE float blockSum256(float v) {
  __shared__ float sh[4];
  int lane = threadIdx.x & 63;
  int w    = threadIdx.x >> 6;
#pragma unroll
  for (int o = 32; o; o >>= 1) v += __shfl_down(v, o, 64);
  __syncthreads();
  if (lane == 0) sh[w] = v;
  __syncthreads();
  return sh[0] + sh[1] + sh[2] + sh[3];
}

// ---------------- row LayerNorm (L <= 1024), bf16 out ----------------
__global__ void k_layernorm(const float* __restrict__ in, unsigned short* __restrict__ out,
                            const float* __restrict__ g, const float* __restrict__ b,
                            int L) {
  __shared__ float row[1024];
  size_t rid = blockIdx.x;
  const float* x = in + rid * (size_t)L;
  float s = 0.f;
  for (int i = threadIdx.x; i < L; i += 256) { float v = x[i]; row[i] = v; s += v; }
  float mean = blockSum256(s) / (float)L;
  float vs = 0.f;
  for (int i = threadIdx.x; i < L; i += 256) { float d = row[i] - mean; vs += d * d; }
  float var = blockSum256(vs) / (float)L;
  float rstd = rsqrtf(var + 1e-5f);
  for (int i = threadIdx.x; i < L; i += 256)
    out[rid * (size_t)L + i] = f2bf((row[i] - mean) * rstd * g[i] + b[i]);
}

// ---------------- LN over sum of two 256-wide rows (mf+mb), bf16 out --------
__global__ void k_layernorm2(const float* __restrict__ mo, unsigned short* __restrict__ out,
                             const float* __restrict__ g, const float* __restrict__ b) {
  size_t rid = blockIdx.x;  // 0..4095
  int e = threadIdx.x;
  float v = mo[rid * 256 + e] + mo[(rid + 4096) * 256 + e];
  float m1 = blockSum256(v) * (1.f / 256.f);
  float d = v - m1;
  float var = blockSum256(d * d) * (1.f / 256.f);
  out[rid * 256 + e] = f2bf(d * rsqrtf(var + 1e-5f) * g[e] + b[e]);
}

// ---------------- bf16 MFMA GEMM: C[M,N] = epi(A[M,K] @ W[N,K]^T) -----------
// block = 128 thr = 2 waves, tile 64m x 64n; wave computes 32m x 64n
// (8 MFMA per K-step from 2 A-frags x 4 B-frags). grid ((N+63)/64, M/64).
template <int ACT, bool RESADD, bool OUTBF>
__global__ __launch_bounds__(128) void k_mgemm(
    const short* __restrict__ A, int lda,
    const short* __restrict__ W, int ldw,
    const float* __restrict__ bias,
    float* __restrict__ Cf, unsigned short* __restrict__ Cb, int ldc,
    const float* __restrict__ res,
    int M, int N, int K) {
  int l = threadIdx.x & 63, w = threadIdx.x >> 6;
  int bm = blockIdx.y << 6, bn = blockIdx.x << 6;
  int r = l & 15, ko = (l >> 4) << 3;
  const short* Ap = A + (size_t)(bm + (w << 5) + r) * lda + ko;
  const short* Wp = W + (size_t)(bn + r) * ldw + ko;
  f32x4 acc[2][4] = {{{0.f,0.f,0.f,0.f},{0.f,0.f,0.f,0.f},{0.f,0.f,0.f,0.f},{0.f,0.f,0.f,0.f}},
                     {{0.f,0.f,0.f,0.f},{0.f,0.f,0.f,0.f},{0.f,0.f,0.f,0.f},{0.f,0.f,0.f,0.f}}};
#pragma unroll 2
  for (int k0 = 0; k0 < K; k0 += 32) {
    bf16x8 a0 = *reinterpret_cast<const bf16x8*>(Ap + k0);
    bf16x8 a1 = *reinterpret_cast<const bf16x8*>(Ap + (size_t)16 * lda + k0);
#pragma unroll
    for (int t = 0; t < 4; t++) {
      if (bn + t * 16 < N) {
        bf16x8 bv = *reinterpret_cast<const bf16x8*>(Wp + (size_t)(t * 16) * ldw + k0);
        acc[0][t] = __builtin_amdgcn_mfma_f32_16x16x32_bf16(a0, bv, acc[0][t], 0, 0, 0);
        acc[1][t] = __builtin_amdgcn_mfma_f32_16x16x32_bf16(a1, bv, acc[1][t], 0, 0, 0);
      }
    }
  }
#pragma unroll
  for (int mf = 0; mf < 2; mf++) {
#pragma unroll
    for (int t = 0; t < 4; t++) {
      if (bn + t * 16 < N) {
        int n = bn + t * 16 + r;
        float bb = bias ? bias[n] : 0.f;
#pragma unroll
        for (int q = 0; q < 4; q++) {
          int m = bm + (w << 5) + (mf << 4) + ((l >> 4) << 2) + q;
          float v = acc[mf][t][q] + bb;
          if (ACT == 1) v = 0.5f * v * (1.f + erff(v * 0.70710678118f));
          size_t oi = (size_t)m * ldc + n;
          if (OUTBF) {
            Cb[oi] = f2bf(v);
          } else {
            if (RESADD) v += res[oi];
            Cf[oi] = v;
          }
        }
      }
    }
  }
}

// ---------------- linear resize T 512 -> 1024 (bf16 in/out into CAT) --------
__global__ void k_resize(const unsigned short* __restrict__ fs,
                         unsigned short* __restrict__ cat) {
  int idx = blockIdx.x * 256 + threadIdx.x;
  int e = idx & 255, t = (idx >> 8) & 1023, b = idx >> 18;
  int j = t >> 1;
  int j0, j1; float w0, w1;
  if ((t & 1) == 0) { j0 = j > 0 ? j - 1 : 0; j1 = j; w0 = 0.25f; w1 = 0.75f; }
  else              { j0 = j; j1 = j < 511 ? j + 1 : 511; w0 = 0.75f; w1 = 0.25f; }
  float v = w0 * bf2f(fs[((size_t)(b << 9) + j0) * 256 + e]) +
            w1 * bf2f(fs[((size_t)(b << 9) + j1) * 256 + e]);
  cat[((size_t)(b << 10) + t) * 512 + 256 + e] = f2bf(v);
}

// ---------------- SE ----------------
__global__ void k_se_part(const float* __restrict__ fc, float* __restrict__ part) {
  int b = blockIdx.y, chunk = blockIdx.x, e = threadIdx.x;
  float s = 0.f;
  for (int j = 0; j < 64; j++) {
    int t = chunk * 64 + j;
    s += fc[((size_t)(b << 10) + t) * 256 + e];
  }
  part[(size_t)(b * 16 + chunk) * 256 + e] = s;
}

__global__ void k_se_fin(const float* __restrict__ part, const float* __restrict__ W1,
                         const float* __restrict__ W2, float* __restrict__ se) {
  int b = blockIdx.x, tid = threadIdx.x;
  __shared__ float mean[256];
  __shared__ float hid[16];
  float s = 0.f;
  for (int c = 0; c < 16; c++) s += part[(size_t)(b * 16 + c) * 256 + tid];
  mean[tid] = s * (1.f / 1024.f);
  __syncthreads();
  int o = tid >> 4, l = tid & 15;
  float p = 0.f;
  for (int e = l; e < 256; e += 16) p += mean[e] * W1[o * 256 + e];
  p += __shfl_xor(p, 1, 64); p += __shfl_xor(p, 2, 64);
  p += __shfl_xor(p, 4, 64); p += __shfl_xor(p, 8, 64);
  if (l == 0) hid[o] = fmaxf(p, 0.f);
  __syncthreads();
  float s2 = 0.f;
  for (int o2 = 0; o2 < 16; o2++) s2 += hid[o2] * W2[tid * 16 + o2];
  se[b * 256 + tid] = 1.f / (1.f + expf(-s2));
}

// ---------------- fused SE-scale + LN_f + LN_1 ----------------
__global__ void k_se_ln(const float* __restrict__ fc, const float* __restrict__ se,
                        const float* __restrict__ gf, const float* __restrict__ bf,
                        const float* __restrict__ g1, const float* __restrict__ b1,
                        float* __restrict__ xout, unsigned short* __restrict__ xnb) {
  size_t rid = blockIdx.x;
  int b = (int)(rid >> 10);
  int e = threadIdx.x;
  float v = fc[rid * 256 + e] * se[b * 256 + e];
  float m1 = blockSum256(v) * (1.f / 256.f);
  float d = v - m1;
  float var = blockSum256(d * d) * (1.f / 256.f);
  float x = d * rsqrtf(var + 1e-5f) * gf[e] + bf[e];
  xout[rid * 256 + e] = x;
  float m2 = blockSum256(x) * (1.f / 256.f);
  float d2 = x - m2;
  float v2 = blockSum256(d2 * d2) * (1.f / 256.f);
  xnb[rid * 256 + e] = f2bf(d2 * rsqrtf(v2 + 1e-5f) * g1[e] + b1[e]);
}

// ---------------- depthwise conv + silu, BOTH dirs per thread, bf16 out -----
// thread handles 4 consecutive d's at one (b,t); reads the 7-row window once.
__global__ void k_conv(const float* __restrict__ xz, const float* __restrict__ cw,
                       const float* __restrict__ cb, unsigned short* __restrict__ ub) {
  int idx = blockIdx.x * 256 + threadIdx.x;  // (b,t,d4): 4*1024*128
  int d4 = idx & 127, t = (idx >> 7) & 1023, b = idx >> 17;
  int base = d4 << 2;
  f32x4 rr[7];
#pragma unroll
  for (int o = 0; o < 7; o++) {
    int tt = t + o - 3;
    if (tt >= 0 && tt < 1024)
      rr[o] = *reinterpret_cast<const f32x4*>(xz + ((size_t)(b << 10) + tt) * 1024 + base);
    else
      rr[o] = (f32x4){0.f, 0.f, 0.f, 0.f};
  }
  f32x4 wv[4];
#pragma unroll
  for (int dd = 0; dd < 4; dd++)
    wv[dd] = *reinterpret_cast<const f32x4*>(cw + (size_t)(base + dd) * 4);
  f32x4 cbv = *reinterpret_cast<const f32x4*>(cb + base);
  f32x4 acc0 = cbv, acc1 = cbv;
#pragma unroll
  for (int k = 0; k < 4; k++) {
#pragma unroll
    for (int dd = 0; dd < 4; dd++) {
      acc0[dd] += rr[k][dd] * wv[dd][k];      // forward: xp[t+k-3]
      acc1[dd] += rr[6 - k][dd] * wv[dd][k];  // backward: x[t+3-k]
    }
  }
  US4 o0, o1;
  {
    float v0 = acc0[0] / (1.f + expf(-acc0[0]));
    float v1 = acc0[1] / (1.f + expf(-acc0[1]));
    float v2 = acc0[2] / (1.f + expf(-acc0[2]));
    float v3 = acc0[3] / (1.f + expf(-acc0[3]));
    o0 = { f2bf(v0), f2bf(v1), f2bf(v2), f2bf(v3) };
    v0 = acc1[0] / (1.f + expf(-acc1[0]));
    v1 = acc1[1] / (1.f + expf(-acc1[1]));
    v2 = acc1[2] / (1.f + expf(-acc1[2]));
    v3 = acc1[3] / (1.f + expf(-acc1[3]));
    o1 = { f2bf(v0), f2bf(v1), f2bf(v2), f2bf(v3) };
  }
  size_t r0 = ((size_t)(b << 10) + t) * 512 + base;           // dir 0
  size_t r1 = ((size_t)((4 + b) << 10) + t) * 512 + base;     // dir 1
  *reinterpret_cast<US4*>(ub + r0) = o0;
  *reinterpret_cast<US4*>(ub + r1) = o1;
}

// ---------------- selective scan (chunked parallel, dt fused, u bf16) -------
// u layout [dir][b][t][d] bf16; xdbl [dir*4+b][t][48] f32.
// dt recomputed in-kernel: dt = softplus(b_dt[d] + dot16(xdbl[t,0:16], Wdt[d,:]))

__global__ __launch_bounds__(256) void k_scan_a(
    const unsigned short* __restrict__ ub, const float* __restrict__ xdbl,
    const float* __restrict__ A_log, const float* __restrict__ Wdt,
    const float* __restrict__ bdt,
    float* __restrict__ SP, float* __restrict__ SH) {
  int chunk = blockIdx.x, b = blockIdx.y;
  int dir = blockIdx.z >> 1, dhalf = blockIdx.z & 1;
  int d = (dhalf << 8) + threadIdx.x;
  __shared__ float Ds[32][16];
  __shared__ float Bs[32][16];
  for (int i = threadIdx.x; i < 512; i += 256) {
    int j = i >> 4, n = i & 15;
    int s = (chunk << 5) + j;
    int t = dir ? (1023 - s) : s;
    size_t row = ((size_t)((dir * 4 + b) * 1024 + t)) * 48;
    Ds[j][n] = xdbl[row + n];
    Bs[j][n] = xdbl[row + 16 + n];
  }
  float a[16], h[16], P[16], wdt[16];
#pragma unroll
  for (int n = 0; n < 16; n++) {
    a[n] = -__expf(A_log[d * 16 + n]);
    wdt[n] = Wdt[d * 16 + n];
    h[n] = 0.f; P[n] = 1.f;
  }
  float dbias = bdt[d];
  __syncthreads();
  size_t base = (size_t)(dir * 4 + b) * 1024;
  int s0 = chunk << 5;
#define ADDR(j) ((base + (dir ? (1023 - (s0 + (j))) : (s0 + (j)))) * 512 + d)
  float u_n = bf2f(ub[ADDR(0)]);
#pragma unroll 4
  for (int j = 0; j < 32; j++) {
    float uv = u_n;
    if (j < 31) u_n = bf2f(ub[ADDR(j + 1)]);
    float sdt = dbias;
#pragma unroll
    for (int rj = 0; rj < 16; rj++) sdt += Ds[j][rj] * wdt[rj];
    float dtv = softplusf(sdt);
    float c1 = dtv * uv;
    const float4* Bp = reinterpret_cast<const float4*>(&Bs[j][0]);
    float4 b0 = Bp[0], b1 = Bp[1], b2 = Bp[2], b3 = Bp[3];
    float Bv[16] = {b0.x, b0.y, b0.z, b0.w, b1.x, b1.y, b1.z, b1.w,
                    b2.x, b2.y, b2.z, b2.w, b3.x, b3.y, b3.z, b3.w};
#pragma unroll
    for (int n = 0; n < 16; n++) {
      float dA = __expf(dtv * a[n]);
      h[n] = dA * h[n] + c1 * Bv[n];
      P[n] *= dA;
    }
  }
  size_t o = ((size_t)((dir * 4 + b) * 32 + chunk) * 512 + d) * 16;
#pragma unroll
  for (int n = 0; n < 16; n++) { SP[o + n] = P[n]; SH[o + n] = h[n]; }
#undef ADDR
}

__global__ __launch_bounds__(256) void k_scan_mid(float* __restrict__ SP,
                                                  const float* __restrict__ SH) {
  int dir = blockIdx.z, b = blockIdx.y;
  int d = (blockIdx.x << 4) + (threadIdx.x >> 4);
  int n = threadIdx.x & 15;
  const size_t cs = 512 * 16;
  size_t base = ((size_t)(dir * 4 + b) * 32) * cs + (size_t)d * 16 + n;
  float H = 0.f;
  float Pv = SP[base], hE = SH[base];
  for (int c = 0; c < 32; c++) {
    float Pc = Pv, hc = hE;
    if (c < 31) { Pv = SP[base + (c + 1) * cs]; hE = SH[base + (c + 1) * cs]; }
    SP[base + (size_t)c * cs] = H;
    H = Pc * H + hc;
  }
}

// Phase B: re-run scan with start state; y = C.h + u*D; silu(z) gate; a7 -> ub
__global__ __launch_bounds__(256) void k_scan_b(
    unsigned short* __restrict__ ub, const float* __restrict__ xdbl,
    const float* __restrict__ A_log, const float* __restrict__ Wdt,
    const float* __restrict__ bdt, const float* __restrict__ Dp,
    const float* __restrict__ xz, const float* __restrict__ SP) {
  int chunk = blockIdx.x, b = blockIdx.y;
  int dir = blockIdx.z >> 1, dhalf = blockIdx.z & 1;
  int d = (dhalf << 8) + threadIdx.x;
  __shared__ float Ds[32][16];
  __shared__ float Bs[32][16];
  __shared__ float Cs[32][16];
  for (int i = threadIdx.x; i < 512; i += 256) {
    int j = i >> 4, n = i & 15;
    int s = (chunk << 5) + j;
    int t = dir ? (1023 - s) : s;
    size_t row = ((size_t)((dir * 4 + b) * 1024 + t)) * 48;
    Ds[j][n] = xdbl[row + n];
    Bs[j][n] = xdbl[row + 16 + n];
    Cs[j][n] = xdbl[row + 32 + n];
  }
  float a[16], h[16], wdt[16];
  size_t so = ((size_t)((dir * 4 + b) * 32 + chunk) * 512 + d) * 16;
#pragma unroll
  for (int n = 0; n < 16; n++) {
    a[n] = -__expf(A_log[d * 16 + n]);
    wdt[n] = Wdt[d * 16 + n];
    h[n] = SP[so + n];
  }
  float dbias = bdt[d];
  float Dval = Dp[d];
  __syncthreads();
  size_t base = (size_t)(dir * 4 + b) * 1024;
  size_t zbase = (size_t)b << 10;
  int s0 = chunk << 5;
#define ADDR(j) ((base + (dir ? (1023 - (s0 + (j))) : (s0 + (j)))) * 512 + d)
#define ZADDR(j) ((((zbase + (dir ? (1023 - (s0 + (j))) : (s0 + (j)))) << 10)) + 512 + d)
  float u_n = bf2f(ub[ADDR(0)]);
  float z_n = xz[ZADDR(0)];
#pragma unroll 4
  for (int j = 0; j < 32; j++) {
    float uv = u_n, zv = z_n;
    if (j < 31) { u_n = bf2f(ub[ADDR(j + 1)]); z_n = xz[ZADDR(j + 1)]; }
    float sdt = dbias;
#pragma unroll
    for (int rj = 0; rj < 16; rj++) sdt += Ds[j][rj] * wdt[rj];
    float dtv = softplusf(sdt);
    float c1 = dtv * uv;
    const float4* Bp = reinterpret_cast<const float4*>(&Bs[j][0]);
    const float4* Cp = reinterpret_cast<const float4*>(&Cs[j][0]);
    float4 b0 = Bp[0], b1 = Bp[1], b2 = Bp[2], b3 = Bp[3];
    float4 c0 = Cp[0], c4 = Cp[1], c8 = Cp[2], cc = Cp[3];
    float Bv[16] = {b0.x, b0.y, b0.z, b0.w, b1.x, b1.y, b1.z, b1.w,
                    b2.x, b2.y, b2.z, b2.w, b3.x, b3.y, b3.z, b3.w};
    float Cv[16] = {c0.x, c0.y, c0.z, c0.w, c4.x, c4.y, c4.z, c4.w,
                    c8.x, c8.y, c8.z, c8.w, cc.x, cc.y, cc.z, cc.w};
    float y0 = 0.f, y1 = 0.f, y2 = 0.f, y3 = 0.f;
#pragma unroll
    for (int n = 0; n < 16; n++) {
      float dA = __expf(dtv * a[n]);
      h[n] = dA * h[n] + c1 * Bv[n];
      float p = h[n] * Cv[n];
      if ((n & 3) == 0) y0 += p; else if ((n & 3) == 1) y1 += p;
      else if ((n & 3) == 2) y2 += p; else y3 += p;
    }
    float y = (y0 + y1) + (y2 + y3) + uv * Dval;
    float sig = 1.f / (1.f + expf(-zv));
    ub[ADDR(j)] = f2bf(y * zv * sig);
  }
#undef ADDR
#undef ZADDR
}

// ---------------- host-side MFMA GEMM dispatcher ----------------
static inline void mgemm(hipStream_t st, int act, bool resadd, bool outbf,
                         const void* A, int lda, const void* W, int ldw,
                         const float* bias, void* Cf, void* Cb, int ldc,
                         const float* res, int M, int N, int K) {
  dim3 g((N + 63) / 64, M / 64), bl(128);
  const short* a = (const short*)A;
  const short* w = (const short*)W;
  float* cf = (float*)Cf;
  unsigned short* cb = (unsigned short*)Cb;
  if (outbf) {
    if (act == 1) hipLaunchKernelGGL((k_mgemm<1, false, true>), g, bl, 0, st, a, lda, w, ldw, bias, cf, cb, ldc, res, M, N, K);
    else          hipLaunchKernelGGL((k_mgemm<0, false, true>), g, bl, 0, st, a, lda, w, ldw, bias, cf, cb, ldc, res, M, N, K);
  } else {
    if (resadd)   hipLaunchKernelGGL((k_mgemm<0, true, false>), g, bl, 0, st, a, lda, w, ldw, bias, cf, cb, ldc, res, M, N, K);
    else          hipLaunchKernelGGL((k_mgemm<0, false, false>), g, bl, 0, st, a, lda, w, ldw, bias, cf, cb, ldc, res, M, N, K);
  }
}

extern "C" void kernel_launch(void* const* d_in, const int* in_sizes, int n_in,
                              void* d_out, int out_size, void* d_ws, size_t ws_size,
                              hipStream_t stream) {
  const float* f_wavlm = (const float*)d_in[0];
  const float* f_sinc  = (const float*)d_in[1];
  const float* ln_w_g  = (const float*)d_in[2];
  const float* ln_w_b  = (const float*)d_in[3];
  const float* ln_s_g  = (const float*)d_in[4];
  const float* ln_s_b  = (const float*)d_in[5];
  const float* W_wp    = (const float*)d_in[6];
  const float* b_wp    = (const float*)d_in[7];
  const float* W_sp    = (const float*)d_in[8];
  const float* b_sp    = (const float*)d_in[9];
  const float* W_fuse  = (const float*)d_in[10];
  const float* b_fuse  = (const float*)d_in[11];
  const float* W_se1   = (const float*)d_in[12];
  const float* W_se2   = (const float*)d_in[13];
  const float* ln_f_g  = (const float*)d_in[14];
  const float* ln_f_b  = (const float*)d_in[15];
  const float* n1_g    = (const float*)d_in[16];
  const float* n1_b    = (const float*)d_in[17];
  const float* n2_g    = (const float*)d_in[18];
  const float* n2_b    = (const float*)d_in[19];
  const float* W_in    = (const float*)d_in[20];
  const float* conv_w  = (const float*)d_in[21];
  const float* conv_b  = (const float*)d_in[22];
  const float* W_xproj = (const float*)d_in[23];
  const float* W_dt    = (const float*)d_in[24];
  const float* b_dt    = (const float*)d_in[25];
  const float* A_log   = (const float*)d_in[26];
  const float* Dp      = (const float*)d_in[27];
  const float* W_out   = (const float*)d_in[28];
  const float* W_ff1   = (const float*)d_in[29];
  const float* b_ff1   = (const float*)d_in[30];
  const float* W_ff2   = (const float*)d_in[31];
  const float* b_ff2   = (const float*)d_in[32];

  float* ws = (float*)d_ws;
  float* pXZ  = ws + OFF_XZ;
  unsigned short* pLNW = (unsigned short*)(ws + SUB_LNW);
  unsigned short* pLNS = (unsigned short*)(ws + SUB_LNS);
  unsigned short* pCAT = (unsigned short*)(ws + SUB_CAT);
  unsigned short* pFSB = (unsigned short*)(ws + SUB_FSB);
  unsigned short* pUB  = (unsigned short*)(ws + OFF_UB);
  float* pXD  = ws + OFF_XD;
  float* pSP  = ws + OFF_SP;
  float* pMO  = ws + OFF_SP;   // reuse after scan_b
  float* pSH  = ws + OFF_SH;
  float* pFC  = ws + OFF_FC;
  float* pRES = ws + OFF_RES;
  unsigned short* pXNB  = (unsigned short*)(ws + OFF_XNB);
  unsigned short* pMB   = (unsigned short*)(ws + OFF_MB);
  unsigned short* pFF1B = (unsigned short*)(ws + OFF_FF1B);
  unsigned short* pWB   = (unsigned short*)(ws + OFF_WB);
  float* pSE1 = ws + OFF_SE1;
  float* pSE2 = ws + OFF_SE2;

  // 0) convert all GEMM weights to bf16
  hipLaunchKernelGGL(k_w2bf, dim3(1320), dim3(256), 0, stream,
                     W_wp, W_sp, W_fuse, W_in, W_xproj, W_out, W_ff1, W_ff2, pWB);

  // 1) LN(f_wavlm) -> LNW bf16 ; fw = @ W_wp^T + b -> CAT cols 0-255 (bf16)
  hipLaunchKernelGGL(k_layernorm, dim3(4096), dim3(256), 0, stream,
                     f_wavlm, pLNW, ln_w_g, ln_w_b, 1024);
  mgemm(stream, 0, false, true, pLNW, 1024, pWB + WB_WP, 1024, b_wp,
        nullptr, pCAT, 512, nullptr, 4096, 256, 1024);

  // 2) LN(f_sinc) -> LNS bf16 ; fs_small -> FSB bf16
  hipLaunchKernelGGL(k_layernorm, dim3(2048), dim3(256), 0, stream,
                     f_sinc, pLNS, ln_s_g, ln_s_b, 64);
  mgemm(stream, 0, false, true, pLNS, 64, pWB + WB_SP, 64, b_sp,
        nullptr, pFSB, 256, nullptr, 2048, 256, 64);

  // 3) resize -> CAT cols 256-511 ; fc = CAT @ W_fuse^T + b (K=512) -> FC f32
  hipLaunchKernelGGL(k_resize, dim3(4096), dim3(256), 0, stream, pFSB, pCAT);
  mgemm(stream, 0, false, false, pCAT, 512, pWB + WB_FUSE, 512, b_fuse,
        pFC, nullptr, 256, nullptr, 4096, 256, 512);

  // 4) SE gate
  hipLaunchKernelGGL(k_se_part, dim3(16, 4), dim3(256), 0, stream, pFC, pSE1);
  hipLaunchKernelGGL(k_se_fin, dim3(4), dim3(256), 0, stream, pSE1, W_se1, W_se2, pSE2);

  // 5) x = LN_f(fc*se) -> RES f32 ; xn = LN_1(x) -> XNB bf16
  hipLaunchKernelGGL(k_se_ln, dim3(4096), dim3(256), 0, stream,
                     pFC, pSE2, ln_f_g, ln_f_b, n1_g, n1_b, pRES, pXNB);

  // 6) xz = xn @ W_in^T -> XZ f32 (overwrites early bf16 scratch)
  mgemm(stream, 0, false, false, pXNB, 256, pWB + WB_IN, 256, nullptr,
        pXZ, nullptr, 1024, nullptr, 4096, 1024, 256);

  // 7) conv+silu both dirs -> UB bf16 (one window read per thread)
  hipLaunchKernelGGL(k_conv, dim3(2048), dim3(256), 0, stream,
                     pXZ, conv_w, conv_b, pUB);

  // 8) xdbl = U @ W_xproj^T (M=8192, N=48) -> XD f32
  mgemm(stream, 0, false, false, pUB, 512, pWB + WB_XPROJ, 512, nullptr,
        pXD, nullptr, 48, nullptr, 8192, 48, 512);

  // 9) chunked scan (both dirs), dt fused in-kernel ; a7 -> UB (in place)
  hipLaunchKernelGGL(k_scan_a, dim3(32, 4, 4), dim3(256), 0, stream,
                     pUB, pXD, A_log, W_dt, b_dt, pSP, pSH);
  hipLaunchKernelGGL(k_scan_mid, dim3(32, 4, 2), dim3(256), 0, stream, pSP, pSH);
  hipLaunchKernelGGL(k_scan_b, dim3(32, 4, 4), dim3(256), 0, stream,
                     pUB, pXD, A_log, W_dt, b_dt, Dp, pXZ, pSP);

  // 10) out GEMM both dirs -> MO f32 ; m = LN_2(mf+mb) -> MB bf16
  mgemm(stream, 0, false, false, pUB, 512, pWB + WB_OUT, 512, nullptr,
        pMO, nullptr, 256, nullptr, 8192, 256, 512);
  hipLaunchKernelGGL(k_layernorm2, dim3(4096), dim3(256), 0, stream, pMO, pMB, n2_g, n2_b);

  // 11) ff1 = gelu(m @ W_ff1^T + b) -> FF1B bf16 ; out = ff1 @ W_ff2^T + b + res
  mgemm(stream, 1, false, true, pMB, 256, pWB + WB_FF1, 256, b_ff1,
        nullptr, pFF1B, 1024, nullptr, 4096, 1024, 256);
  mgemm(stream, 0, true, false, pFF1B, 1024, pWB + WB_FF2, 1024, b_ff2,
        d_out, nullptr, 256, pRES, 4096, 256, 1024);
}

// Round 10
// 359.941 us; speedup vs baseline: 3.4006x; 1.1168x over previous
//
#include <hip/hip_runtime.h>
#include <math.h>

#define DEV_INLINE __device__ __forceinline__

typedef __attribute__((ext_vector_type(8))) short bf16x8;
typedef __attribute__((ext_vector_type(4))) float f32x4;

struct US4 { unsigned short x, y, z, w; };

DEV_INLINE unsigned short f2bf(float f) {
  union { float f; unsigned u; } v; v.f = f;
  unsigned r = v.u + 0x7fff + ((v.u >> 16) & 1);
  return (unsigned short)(r >> 16);
}
DEV_INLINE float bf2f(unsigned short h) {
  union { unsigned u; float f; } v; v.u = ((unsigned)h) << 16;
  return v.f;
}
DEV_INLINE float softplusf(float x) {
  return x > 20.f ? x : __logf(1.f + __expf(x));
}

// ---------------- workspace layout (float offsets) ----------------
static constexpr size_t OFF_XZ   = 0;          // 4M fl region, multi-use:
static constexpr size_t SUB_LNW  = 0;          //   bf16 4096x1024 (2M fl) early
static constexpr size_t SUB_LNS  = 2097152;    //   bf16 2048x64 early
static constexpr size_t SUB_CAT  = 2162688;    //   bf16 4096x512 early
static constexpr size_t SUB_FSB  = 3211264;    //   bf16 2048x256 early
static constexpr size_t SUB_XM   = 0;          //   f32 4096x512 (2M fl) after step 6
static constexpr size_t SUB_ZB   = 2097152;    //   bf16 4096x512 silu(z) (1M fl)
static constexpr size_t OFF_UB   = 4194304;    // bf16 8192x512 (2M fl): conv out -> a7
static constexpr size_t OFF_XD   = 6291456;    // 393,216 fl: xdbl f32 (8192x48)
static constexpr size_t OFF_SP   = 6684672;    // 2M fl: scan products/starts; later MO f32
static constexpr size_t OFF_SH   = 8781824;    // 2M fl
static constexpr size_t OFF_FC   = 10878976;   // 1M fl
static constexpr size_t OFF_RES  = 11927552;   // 1M fl
static constexpr size_t OFF_XNB  = 12976128;   // bf16 4096x256 (512K fl)
static constexpr size_t OFF_MB   = 13500416;   // bf16 4096x256 (512K fl)
static constexpr size_t OFF_FF1B = 14024704;   // bf16 4096x1024 (2M fl)
static constexpr size_t OFF_WB   = 16121856;   // bf16 weights (675,840 fl)
static constexpr size_t OFF_SE1  = 16797696;   // 16K fl
static constexpr size_t OFF_SE2  = 16814080;   // 1K fl

// bf16 weight sub-offsets (ushort units) inside WB
static constexpr size_t WB_WP    = 0;          // 256x1024
static constexpr size_t WB_SP    = 262144;     // 256x64
static constexpr size_t WB_FUSE  = 278528;     // 256x512
static constexpr size_t WB_IN    = 409600;     // 1024x256
static constexpr size_t WB_XPROJ = 671744;     // 48x512
static constexpr size_t WB_OUT   = 696320;     // 256x512
static constexpr size_t WB_FF1   = 827392;     // 1024x256
static constexpr size_t WB_FF2   = 1089536;    // 256x1024

// ---------------- weight f32 -> bf16 converter ----------------
__global__ void k_w2bf(const float* __restrict__ w0, const float* __restrict__ w1,
                       const float* __restrict__ w2, const float* __restrict__ w3,
                       const float* __restrict__ w4, const float* __restrict__ w5,
                       const float* __restrict__ w6, const float* __restrict__ w7,
                       unsigned short* __restrict__ dst) {
  int i = blockIdx.x * 256 + threadIdx.x;  // float4 index, total 337,920
  const float* s; size_t dbase; int rel;
  if      (i <  65536) { s = w0; rel = i;          dbase = WB_WP; }
  else if (i <  69632) { s = w1; rel = i -  65536; dbase = WB_SP; }
  else if (i < 102400) { s = w2; rel = i -  69632; dbase = WB_FUSE; }
  else if (i < 167936) { s = w3; rel = i - 102400; dbase = WB_IN; }
  else if (i < 174080) { s = w4; rel = i - 167936; dbase = WB_XPROJ; }
  else if (i < 206848) { s = w5; rel = i - 174080; dbase = WB_OUT; }
  else if (i < 272384) { s = w6; rel = i - 206848; dbase = WB_FF1; }
  else                 { s = w7; rel = i - 272384; dbase = WB_FF2; }
  float4 v = reinterpret_cast<const float4*>(s)[rel];
  US4 o = { f2bf(v.x), f2bf(v.y), f2bf(v.z), f2bf(v.w) };
  reinterpret_cast<US4*>(dst + dbase)[rel] = o;
}

// ---------------- block-wide sum, blockDim == 256 ----------------
DEV_INLINE float blockSum256(float v) {
  __shared__ float sh[4];
  int lane = threadIdx.x & 63;
  int w    = threadIdx.x >> 6;
#pragma unroll
  for (int o = 32; o; o >>= 1) v += __shfl_down(v, o, 64);
  __syncthreads();
  if (lane == 0) sh[w] = v;
  __syncthreads();
  return sh[0] + sh[1] + sh[2] + sh[3];
}

// ---------------- row LayerNorm (L <= 1024), bf16 out ----------------
__global__ void k_layernorm(const float* __restrict__ in, unsigned short* __restrict__ out,
                            const float* __restrict__ g, const float* __restrict__ b,
                            int L) {
  __shared__ float row[1024];
  size_t rid = blockIdx.x;
  const float* x = in + rid * (size_t)L;
  float s = 0.f;
  for (int i = threadIdx.x; i < L; i += 256) { float v = x[i]; row[i] = v; s += v; }
  float mean = blockSum256(s) / (float)L;
  float vs = 0.f;
  for (int i = threadIdx.x; i < L; i += 256) { float d = row[i] - mean; vs += d * d; }
  float var = blockSum256(vs) / (float)L;
  float rstd = rsqrtf(var + 1e-5f);
  for (int i = threadIdx.x; i < L; i += 256)
    out[rid * (size_t)L + i] = f2bf((row[i] - mean) * rstd * g[i] + b[i]);
}

// ---------------- LN over sum of two 256-wide rows (mf+mb), bf16 out --------
__global__ void k_layernorm2(const float* __restrict__ mo, unsigned short* __restrict__ out,
                             const float* __restrict__ g, const float* __restrict__ b) {
  size_t rid = blockIdx.x;  // 0..4095
  int e = threadIdx.x;
  float v = mo[rid * 256 + e] + mo[(rid + 4096) * 256 + e];
  float m1 = blockSum256(v) * (1.f / 256.f);
  float d = v - m1;
  float var = blockSum256(d * d) * (1.f / 256.f);
  out[rid * 256 + e] = f2bf(d * rsqrtf(var + 1e-5f) * g[e] + b[e]);
}

// ---------------- bf16 MFMA GEMM with K-split --------------------------------
// block = 256 thr = 4 waves. KS=4: block tile 32m x 64n, each wave = full
// m-range over K/4 (grid y = M/32). KS=2: block tile 64m x 64n, w&1 = m-half,
// w>>1 = k-half (grid y = M/64). Partial sums combined through LDS.
// OUTMODE: 0 = f32 (opt. RESADD), 1 = bf16, 2 = split xm f32 / silu(z) bf16.
template <int ACT, bool RESADD, int OUTMODE, int KS>
__global__ __launch_bounds__(256) void k_mgemm(
    const short* __restrict__ A, int lda,
    const short* __restrict__ W, int ldw,
    const float* __restrict__ bias,
    float* __restrict__ Cf, unsigned short* __restrict__ Cb, int ldc,
    const float* __restrict__ res,
    int M, int N, int K) {
  __shared__ float red[(KS == 2 ? 2 : 3)][32][65];
  int l = threadIdx.x & 63, w = threadIdx.x >> 6;
  int wm = (KS == 2) ? (w & 1) : 0;
  int wk = (KS == 2) ? (w >> 1) : w;
  int bm = (KS == 2) ? ((blockIdx.y << 6) + (wm << 5)) : (blockIdx.y << 5);
  int bn = blockIdx.x << 6;
  int r = l & 15, rrow = (l >> 4) << 2, ko = (l >> 4) << 3;
  int KH = K / KS;
  const short* Ap = A + (size_t)(bm + r) * lda + wk * KH + ko;
  const short* Wp = W + (size_t)(bn + r) * ldw + wk * KH + ko;
  f32x4 acc[2][4] = {{{0.f,0.f,0.f,0.f},{0.f,0.f,0.f,0.f},{0.f,0.f,0.f,0.f},{0.f,0.f,0.f,0.f}},
                     {{0.f,0.f,0.f,0.f},{0.f,0.f,0.f,0.f},{0.f,0.f,0.f,0.f},{0.f,0.f,0.f,0.f}}};
#pragma unroll 2
  for (int k0 = 0; k0 < KH; k0 += 32) {
    bf16x8 a0 = *reinterpret_cast<const bf16x8*>(Ap + k0);
    bf16x8 a1 = *reinterpret_cast<const bf16x8*>(Ap + (size_t)16 * lda + k0);
#pragma unroll
    for (int t = 0; t < 4; t++) {
      if (bn + t * 16 < N) {
        bf16x8 bv = *reinterpret_cast<const bf16x8*>(Wp + (size_t)(t * 16) * ldw + k0);
        acc[0][t] = __builtin_amdgcn_mfma_f32_16x16x32_bf16(a0, bv, acc[0][t], 0, 0, 0);
        acc[1][t] = __builtin_amdgcn_mfma_f32_16x16x32_bf16(a1, bv, acc[1][t], 0, 0, 0);
      }
    }
  }
  if (wk > 0) {
    int slot = (KS == 2) ? wm : (wk - 1);
#pragma unroll
    for (int mf = 0; mf < 2; mf++)
#pragma unroll
      for (int t = 0; t < 4; t++)
#pragma unroll
        for (int q = 0; q < 4; q++)
          red[slot][(mf << 4) + rrow + q][t * 16 + r] = acc[mf][t][q];
  }
  __syncthreads();
  if (wk == 0) {
#pragma unroll
    for (int mf = 0; mf < 2; mf++) {
#pragma unroll
      for (int t = 0; t < 4; t++) {
        if (bn + t * 16 < N) {
          int n = bn + t * 16 + r;
          float bb = bias ? bias[n] : 0.f;
#pragma unroll
          for (int q = 0; q < 4; q++) {
            int rw = (mf << 4) + rrow + q, cl = t * 16 + r;
            float v = acc[mf][t][q];
            if (KS == 2) v += red[wm][rw][cl];
            else         v += red[0][rw][cl] + red[1][rw][cl] + red[2][rw][cl];
            v += bb;
            if (ACT == 1) v = 0.5f * v * (1.f + erff(v * 0.70710678118f));
            int m = bm + rw;
            if (OUTMODE == 0) {
              size_t oi = (size_t)m * ldc + n;
              if (RESADD) v += res[oi];
              Cf[oi] = v;
            } else if (OUTMODE == 1) {
              Cb[(size_t)m * ldc + n] = f2bf(v);
            } else {  // split: n<512 xm f32, n>=512 silu(z) bf16
              if (n < 512) Cf[(size_t)m * 512 + n] = v;
              else Cb[(size_t)m * 512 + (n - 512)] = f2bf(v / (1.f + __expf(-v)));
            }
          }
        }
      }
    }
  }
}

// ---------------- linear resize T 512 -> 1024 (bf16 in/out into CAT) --------
__global__ void k_resize(const unsigned short* __restrict__ fs,
                         unsigned short* __restrict__ cat) {
  int idx = blockIdx.x * 256 + threadIdx.x;
  int e = idx & 255, t = (idx >> 8) & 1023, b = idx >> 18;
  int j = t >> 1;
  int j0, j1; float w0, w1;
  if ((t & 1) == 0) { j0 = j > 0 ? j - 1 : 0; j1 = j; w0 = 0.25f; w1 = 0.75f; }
  else              { j0 = j; j1 = j < 511 ? j + 1 : 511; w0 = 0.75f; w1 = 0.25f; }
  float v = w0 * bf2f(fs[((size_t)(b << 9) + j0) * 256 + e]) +
            w1 * bf2f(fs[((size_t)(b << 9) + j1) * 256 + e]);
  cat[((size_t)(b << 10) + t) * 512 + 256 + e] = f2bf(v);
}

// ---------------- SE ----------------
__global__ void k_se_part(const float* __restrict__ fc, float* __restrict__ part) {
  int b = blockIdx.y, chunk = blockIdx.x, e = threadIdx.x;
  float s = 0.f;
  for (int j = 0; j < 64; j++) {
    int t = chunk * 64 + j;
    s += fc[((size_t)(b << 10) + t) * 256 + e];
  }
  part[(size_t)(b * 16 + chunk) * 256 + e] = s;
}

__global__ void k_se_fin(const float* __restrict__ part, const float* __restrict__ W1,
                         const float* __restrict__ W2, float* __restrict__ se) {
  int b = blockIdx.x, tid = threadIdx.x;
  __shared__ float mean[256];
  __shared__ float hid[16];
  float s = 0.f;
  for (int c = 0; c < 16; c++) s += part[(size_t)(b * 16 + c) * 256 + tid];
  mean[tid] = s * (1.f / 1024.f);
  __syncthreads();
  int o = tid >> 4, l = tid & 15;
  float p = 0.f;
  for (int e = l; e < 256; e += 16) p += mean[e] * W1[o * 256 + e];
  p += __shfl_xor(p, 1, 64); p += __shfl_xor(p, 2, 64);
  p += __shfl_xor(p, 4, 64); p += __shfl_xor(p, 8, 64);
  if (l == 0) hid[o] = fmaxf(p, 0.f);
  __syncthreads();
  float s2 = 0.f;
  for (int o2 = 0; o2 < 16; o2++) s2 += hid[o2] * W2[tid * 16 + o2];
  se[b * 256 + tid] = 1.f / (1.f + expf(-s2));
}

// ---------------- fused SE-scale + LN_f + LN_1 ----------------
__global__ void k_se_ln(const float* __restrict__ fc, const float* __restrict__ se,
                        const float* __restrict__ gf, const float* __restrict__ bf,
                        const float* __restrict__ g1, const float* __restrict__ b1,
                        float* __restrict__ xout, unsigned short* __restrict__ xnb) {
  size_t rid = blockIdx.x;
  int b = (int)(rid >> 10);
  int e = threadIdx.x;
  float v = fc[rid * 256 + e] * se[b * 256 + e];
  float m1 = blockSum256(v) * (1.f / 256.f);
  float d = v - m1;
  float var = blockSum256(d * d) * (1.f / 256.f);
  float x = d * rsqrtf(var + 1e-5f) * gf[e] + bf[e];
  xout[rid * 256 + e] = x;
  float m2 = blockSum256(x) * (1.f / 256.f);
  float d2 = x - m2;
  float v2 = blockSum256(d2 * d2) * (1.f / 256.f);
  xnb[rid * 256 + e] = f2bf(d2 * rsqrtf(v2 + 1e-5f) * g1[e] + b1[e]);
}

// ---------------- depthwise conv + silu, BOTH dirs per thread, bf16 out -----
// xm: [4096][512] f32. thread handles 4 consecutive d's at one (b,t).
__global__ void k_conv(const float* __restrict__ xm, const float* __restrict__ cw,
                       const float* __restrict__ cb, unsigned short* __restrict__ ub) {
  int idx = blockIdx.x * 256 + threadIdx.x;  // (b,t,d4): 4*1024*128
  int d4 = idx & 127, t = (idx >> 7) & 1023, b = idx >> 17;
  int base = d4 << 2;
  f32x4 rr[7];
#pragma unroll
  for (int o = 0; o < 7; o++) {
    int tt = t + o - 3;
    if (tt >= 0 && tt < 1024)
      rr[o] = *reinterpret_cast<const f32x4*>(xm + ((size_t)(b << 10) + tt) * 512 + base);
    else
      rr[o] = (f32x4){0.f, 0.f, 0.f, 0.f};
  }
  f32x4 wv[4];
#pragma unroll
  for (int dd = 0; dd < 4; dd++)
    wv[dd] = *reinterpret_cast<const f32x4*>(cw + (size_t)(base + dd) * 4);
  f32x4 cbv = *reinterpret_cast<const f32x4*>(cb + base);
  f32x4 acc0 = cbv, acc1 = cbv;
#pragma unroll
  for (int k = 0; k < 4; k++) {
#pragma unroll
    for (int dd = 0; dd < 4; dd++) {
      acc0[dd] += rr[k][dd] * wv[dd][k];      // forward: xp[t+k-3]
      acc1[dd] += rr[6 - k][dd] * wv[dd][k];  // backward: x[t+3-k]
    }
  }
  US4 o0, o1;
  {
    float v0 = acc0[0] / (1.f + expf(-acc0[0]));
    float v1 = acc0[1] / (1.f + expf(-acc0[1]));
    float v2 = acc0[2] / (1.f + expf(-acc0[2]));
    float v3 = acc0[3] / (1.f + expf(-acc0[3]));
    o0 = { f2bf(v0), f2bf(v1), f2bf(v2), f2bf(v3) };
    v0 = acc1[0] / (1.f + expf(-acc1[0]));
    v1 = acc1[1] / (1.f + expf(-acc1[1]));
    v2 = acc1[2] / (1.f + expf(-acc1[2]));
    v3 = acc1[3] / (1.f + expf(-acc1[3]));
    o1 = { f2bf(v0), f2bf(v1), f2bf(v2), f2bf(v3) };
  }
  size_t r0 = ((size_t)(b << 10) + t) * 512 + base;           // dir 0
  size_t r1 = ((size_t)((4 + b) << 10) + t) * 512 + base;     // dir 1
  *reinterpret_cast<US4*>(ub + r0) = o0;
  *reinterpret_cast<US4*>(ub + r1) = o1;
}

// ---------------- selective scan (chunked parallel, dt fused, u bf16) -------
__global__ __launch_bounds__(256) void k_scan_a(
    const unsigned short* __restrict__ ub, const float* __restrict__ xdbl,
    const float* __restrict__ A_log, const float* __restrict__ Wdt,
    const float* __restrict__ bdt,
    float* __restrict__ SP, float* __restrict__ SH) {
  int chunk = blockIdx.x, b = blockIdx.y;
  int dir = blockIdx.z >> 1, dhalf = blockIdx.z & 1;
  int d = (dhalf << 8) + threadIdx.x;
  __shared__ float Ds[32][16];
  __shared__ float Bs[32][16];
  for (int i = threadIdx.x; i < 512; i += 256) {
    int j = i >> 4, n = i & 15;
    int s = (chunk << 5) + j;
    int t = dir ? (1023 - s) : s;
    size_t row = ((size_t)((dir * 4 + b) * 1024 + t)) * 48;
    Ds[j][n] = xdbl[row + n];
    Bs[j][n] = xdbl[row + 16 + n];
  }
  float a[16], h[16], P[16], wdt[16];
#pragma unroll
  for (int n = 0; n < 16; n++) {
    a[n] = -__expf(A_log[d * 16 + n]);
    wdt[n] = Wdt[d * 16 + n];
    h[n] = 0.f; P[n] = 1.f;
  }
  float dbias = bdt[d];
  __syncthreads();
  size_t base = (size_t)(dir * 4 + b) * 1024;
  int s0 = chunk << 5;
#define ADDR(j) ((base + (dir ? (1023 - (s0 + (j))) : (s0 + (j)))) * 512 + d)
  float u_n = bf2f(ub[ADDR(0)]);
#pragma unroll 4
  for (int j = 0; j < 32; j++) {
    float uv = u_n;
    if (j < 31) u_n = bf2f(ub[ADDR(j + 1)]);
    float sdt = dbias;
#pragma unroll
    for (int rj = 0; rj < 16; rj++) sdt += Ds[j][rj] * wdt[rj];
    float dtv = softplusf(sdt);
    float c1 = dtv * uv;
    const float4* Bp = reinterpret_cast<const float4*>(&Bs[j][0]);
    float4 b0 = Bp[0], b1 = Bp[1], b2 = Bp[2], b3 = Bp[3];
    float Bv[16] = {b0.x, b0.y, b0.z, b0.w, b1.x, b1.y, b1.z, b1.w,
                    b2.x, b2.y, b2.z, b2.w, b3.x, b3.y, b3.z, b3.w};
#pragma unroll
    for (int n = 0; n < 16; n++) {
      float dA = __expf(dtv * a[n]);
      h[n] = dA * h[n] + c1 * Bv[n];
      P[n] *= dA;
    }
  }
  size_t o = ((size_t)((dir * 4 + b) * 32 + chunk) * 512 + d) * 16;
#pragma unroll
  for (int n = 0; n < 16; n++) { SP[o + n] = P[n]; SH[o + n] = h[n]; }
#undef ADDR
}

__global__ __launch_bounds__(256) void k_scan_mid(float* __restrict__ SP,
                                                  const float* __restrict__ SH) {
  int dir = blockIdx.z, b = blockIdx.y;
  int d = (blockIdx.x << 4) + (threadIdx.x >> 4);
  int n = threadIdx.x & 15;
  const size_t cs = 512 * 16;
  size_t base = ((size_t)(dir * 4 + b) * 32) * cs + (size_t)d * 16 + n;
  float H = 0.f;
  float Pv = SP[base], hE = SH[base];
  for (int c = 0; c < 32; c++) {
    float Pc = Pv, hc = hE;
    if (c < 31) { Pv = SP[base + (c + 1) * cs]; hE = SH[base + (c + 1) * cs]; }
    SP[base + (size_t)c * cs] = H;
    H = Pc * H + hc;
  }
}

// Phase B: re-run scan with start state; y = C.h + u*D; pre-gated silu(z) bf16
__global__ __launch_bounds__(256) void k_scan_b(
    unsigned short* __restrict__ ub, const float* __restrict__ xdbl,
    const float* __restrict__ A_log, const float* __restrict__ Wdt,
    const float* __restrict__ bdt, const float* __restrict__ Dp,
    const unsigned short* __restrict__ zb, const float* __restrict__ SP) {
  int chunk = blockIdx.x, b = blockIdx.y;
  int dir = blockIdx.z >> 1, dhalf = blockIdx.z & 1;
  int d = (dhalf << 8) + threadIdx.x;
  __shared__ float Ds[32][16];
  __shared__ float Bs[32][16];
  __shared__ float Cs[32][16];
  for (int i = threadIdx.x; i < 512; i += 256) {
    int j = i >> 4, n = i & 15;
    int s = (chunk << 5) + j;
    int t = dir ? (1023 - s) : s;
    size_t row = ((size_t)((dir * 4 + b) * 1024 + t)) * 48;
    Ds[j][n] = xdbl[row + n];
    Bs[j][n] = xdbl[row + 16 + n];
    Cs[j][n] = xdbl[row + 32 + n];
  }
  float a[16], h[16], wdt[16];
  size_t so = ((size_t)((dir * 4 + b) * 32 + chunk) * 512 + d) * 16;
#pragma unroll
  for (int n = 0; n < 16; n++) {
    a[n] = -__expf(A_log[d * 16 + n]);
    wdt[n] = Wdt[d * 16 + n];
    h[n] = SP[so + n];
  }
  float dbias = bdt[d];
  float Dval = Dp[d];
  __syncthreads();
  size_t base = (size_t)(dir * 4 + b) * 1024;
  size_t zbase = (size_t)b << 10;
  int s0 = chunk << 5;
#define ADDR(j) ((base + (dir ? (1023 - (s0 + (j))) : (s0 + (j)))) * 512 + d)
#define ZADDR(j) (((zbase + (dir ? (1023 - (s0 + (j))) : (s0 + (j)))) * 512) + d)
  float u_n = bf2f(ub[ADDR(0)]);
  float z_n = bf2f(zb[ZADDR(0)]);
#pragma unroll 4
  for (int j = 0; j < 32; j++) {
    float uv = u_n, szv = z_n;
    if (j < 31) { u_n = bf2f(ub[ADDR(j + 1)]); z_n = bf2f(zb[ZADDR(j + 1)]); }
    float sdt = dbias;
#pragma unroll
    for (int rj = 0; rj < 16; rj++) sdt += Ds[j][rj] * wdt[rj];
    float dtv = softplusf(sdt);
    float c1 = dtv * uv;
    const float4* Bp = reinterpret_cast<const float4*>(&Bs[j][0]);
    const float4* Cp = reinterpret_cast<const float4*>(&Cs[j][0]);
    float4 b0 = Bp[0], b1 = Bp[1], b2 = Bp[2], b3 = Bp[3];
    float4 c0 = Cp[0], c4 = Cp[1], c8 = Cp[2], cc = Cp[3];
    float Bv[16] = {b0.x, b0.y, b0.z, b0.w, b1.x, b1.y, b1.z, b1.w,
                    b2.x, b2.y, b2.z, b2.w, b3.x, b3.y, b3.z, b3.w};
    float Cv[16] = {c0.x, c0.y, c0.z, c0.w, c4.x, c4.y, c4.z, c4.w,
                    c8.x, c8.y, c8.z, c8.w, cc.x, cc.y, cc.z, cc.w};
    float y0 = 0.f, y1 = 0.f, y2 = 0.f, y3 = 0.f;
#pragma unroll
    for (int n = 0; n < 16; n++) {
      float dA = __expf(dtv * a[n]);
      h[n] = dA * h[n] + c1 * Bv[n];
      float p = h[n] * Cv[n];
      if ((n & 3) == 0) y0 += p; else if ((n & 3) == 1) y1 += p;
      else if ((n & 3) == 2) y2 += p; else y3 += p;
    }
    float y = (y0 + y1) + (y2 + y3) + uv * Dval;
    ub[ADDR(j)] = f2bf(y * szv);
  }
#undef ADDR
#undef ZADDR
}

// ---------------- host-side MFMA GEMM dispatcher ----------------
// outmode: 0 f32, 1 bf16, 2 siluz-split
static inline void mgemm(hipStream_t st, int act, bool resadd, int outmode,
                         const void* A, int lda, const void* W, int ldw,
                         const float* bias, void* Cf, void* Cb, int ldc,
                         const float* res, int M, int N, int K) {
  bool ks4 = (K >= 256);
  dim3 g((N + 63) / 64, ks4 ? (M / 32) : (M / 64)), bl(256);
  const short* a = (const short*)A;
  const short* w = (const short*)W;
  float* cf = (float*)Cf;
  unsigned short* cb = (unsigned short*)Cb;
  if (outmode == 2) {
    hipLaunchKernelGGL((k_mgemm<0, false, 2, 4>), g, bl, 0, st, a, lda, w, ldw, bias, cf, cb, ldc, res, M, N, K);
  } else if (outmode == 1) {
    if (act == 1)      hipLaunchKernelGGL((k_mgemm<1, false, 1, 4>), g, bl, 0, st, a, lda, w, ldw, bias, cf, cb, ldc, res, M, N, K);
    else if (ks4)      hipLaunchKernelGGL((k_mgemm<0, false, 1, 4>), g, bl, 0, st, a, lda, w, ldw, bias, cf, cb, ldc, res, M, N, K);
    else               hipLaunchKernelGGL((k_mgemm<0, false, 1, 2>), g, bl, 0, st, a, lda, w, ldw, bias, cf, cb, ldc, res, M, N, K);
  } else {
    if (resadd)        hipLaunchKernelGGL((k_mgemm<0, true, 0, 4>), g, bl, 0, st, a, lda, w, ldw, bias, cf, cb, ldc, res, M, N, K);
    else               hipLaunchKernelGGL((k_mgemm<0, false, 0, 4>), g, bl, 0, st, a, lda, w, ldw, bias, cf, cb, ldc, res, M, N, K);
  }
}

extern "C" void kernel_launch(void* const* d_in, const int* in_sizes, int n_in,
                              void* d_out, int out_size, void* d_ws, size_t ws_size,
                              hipStream_t stream) {
  const float* f_wavlm = (const float*)d_in[0];
  const float* f_sinc  = (const float*)d_in[1];
  const float* ln_w_g  = (const float*)d_in[2];
  const float* ln_w_b  = (const float*)d_in[3];
  const float* ln_s_g  = (const float*)d_in[4];
  const float* ln_s_b  = (const float*)d_in[5];
  const float* W_wp    = (const float*)d_in[6];
  const float* b_wp    = (const float*)d_in[7];
  const float* W_sp    = (const float*)d_in[8];
  const float* b_sp    = (const float*)d_in[9];
  const float* W_fuse  = (const float*)d_in[10];
  const float* b_fuse  = (const float*)d_in[11];
  const float* W_se1   = (const float*)d_in[12];
  const float* W_se2   = (const float*)d_in[13];
  const float* ln_f_g  = (const float*)d_in[14];
  const float* ln_f_b  = (const float*)d_in[15];
  const float* n1_g    = (const float*)d_in[16];
  const float* n1_b    = (const float*)d_in[17];
  const float* n2_g    = (const float*)d_in[18];
  const float* n2_b    = (const float*)d_in[19];
  const float* W_in    = (const float*)d_in[20];
  const float* conv_w  = (const float*)d_in[21];
  const float* conv_b  = (const float*)d_in[22];
  const float* W_xproj = (const float*)d_in[23];
  const float* W_dt    = (const float*)d_in[24];
  const float* b_dt    = (const float*)d_in[25];
  const float* A_log   = (const float*)d_in[26];
  const float* Dp      = (const float*)d_in[27];
  const float* W_out   = (const float*)d_in[28];
  const float* W_ff1   = (const float*)d_in[29];
  const float* b_ff1   = (const float*)d_in[30];
  const float* W_ff2   = (const float*)d_in[31];
  const float* b_ff2   = (const float*)d_in[32];

  float* ws = (float*)d_ws;
  unsigned short* pLNW = (unsigned short*)(ws + SUB_LNW);
  unsigned short* pLNS = (unsigned short*)(ws + SUB_LNS);
  unsigned short* pCAT = (unsigned short*)(ws + SUB_CAT);
  unsigned short* pFSB = (unsigned short*)(ws + SUB_FSB);
  float* pXM = ws + SUB_XM;
  unsigned short* pZB = (unsigned short*)(ws + SUB_ZB);
  unsigned short* pUB  = (unsigned short*)(ws + OFF_UB);
  float* pXD  = ws + OFF_XD;
  float* pSP  = ws + OFF_SP;
  float* pMO  = ws + OFF_SP;   // reuse after scan_b
  float* pSH  = ws + OFF_SH;
  float* pFC  = ws + OFF_FC;
  float* pRES = ws + OFF_RES;
  unsigned short* pXNB  = (unsigned short*)(ws + OFF_XNB);
  unsigned short* pMB   = (unsigned short*)(ws + OFF_MB);
  unsigned short* pFF1B = (unsigned short*)(ws + OFF_FF1B);
  unsigned short* pWB   = (unsigned short*)(ws + OFF_WB);
  float* pSE1 = ws + OFF_SE1;
  float* pSE2 = ws + OFF_SE2;

  // 0) convert all GEMM weights to bf16
  hipLaunchKernelGGL(k_w2bf, dim3(1320), dim3(256), 0, stream,
                     W_wp, W_sp, W_fuse, W_in, W_xproj, W_out, W_ff1, W_ff2, pWB);

  // 1) LN(f_wavlm) -> LNW bf16 ; fw = @ W_wp^T + b -> CAT cols 0-255 (bf16)
  hipLaunchKernelGGL(k_layernorm, dim3(4096), dim3(256), 0, stream,
                     f_wavlm, pLNW, ln_w_g, ln_w_b, 1024);
  mgemm(stream, 0, false, 1, pLNW, 1024, pWB + WB_WP, 1024, b_wp,
        nullptr, pCAT, 512, nullptr, 4096, 256, 1024);

  // 2) LN(f_sinc) -> LNS bf16 ; fs_small -> FSB bf16
  hipLaunchKernelGGL(k_layernorm, dim3(2048), dim3(256), 0, stream,
                     f_sinc, pLNS, ln_s_g, ln_s_b, 64);
  mgemm(stream, 0, false, 1, pLNS, 64, pWB + WB_SP, 64, b_sp,
        nullptr, pFSB, 256, nullptr, 2048, 256, 64);

  // 3) resize -> CAT cols 256-511 ; fc = CAT @ W_fuse^T + b (K=512) -> FC f32
  hipLaunchKernelGGL(k_resize, dim3(4096), dim3(256), 0, stream, pFSB, pCAT);
  mgemm(stream, 0, false, 0, pCAT, 512, pWB + WB_FUSE, 512, b_fuse,
        pFC, nullptr, 256, nullptr, 4096, 256, 512);

  // 4) SE gate
  hipLaunchKernelGGL(k_se_part, dim3(16, 4), dim3(256), 0, stream, pFC, pSE1);
  hipLaunchKernelGGL(k_se_fin, dim3(4), dim3(256), 0, stream, pSE1, W_se1, W_se2, pSE2);

  // 5) x = LN_f(fc*se) -> RES f32 ; xn = LN_1(x) -> XNB bf16
  hipLaunchKernelGGL(k_se_ln, dim3(4096), dim3(256), 0, stream,
                     pFC, pSE2, ln_f_g, ln_f_b, n1_g, n1_b, pRES, pXNB);

  // 6) xz = xn @ W_in^T: xm half -> XM f32, z half -> silu bf16 ZB
  mgemm(stream, 0, false, 2, pXNB, 256, pWB + WB_IN, 256, nullptr,
        pXM, pZB, 512, nullptr, 4096, 1024, 256);

  // 7) conv+silu both dirs -> UB bf16
  hipLaunchKernelGGL(k_conv, dim3(2048), dim3(256), 0, stream,
                     pXM, conv_w, conv_b, pUB);

  // 8) xdbl = U @ W_xproj^T (M=8192, N=48) -> XD f32
  mgemm(stream, 0, false, 0, pUB, 512, pWB + WB_XPROJ, 512, nullptr,
        pXD, nullptr, 48, nullptr, 8192, 48, 512);

  // 9) chunked scan (both dirs), dt fused in-kernel ; a7 -> UB (in place)
  hipLaunchKernelGGL(k_scan_a, dim3(32, 4, 4), dim3(256), 0, stream,
                     pUB, pXD, A_log, W_dt, b_dt, pSP, pSH);
  hipLaunchKernelGGL(k_scan_mid, dim3(32, 4, 2), dim3(256), 0, stream, pSP, pSH);
  hipLaunchKernelGGL(k_scan_b, dim3(32, 4, 4), dim3(256), 0, stream,
                     pUB, pXD, A_log, W_dt, b_dt, Dp, pZB, pSP);

  // 10) out GEMM both dirs -> MO f32 ; m = LN_2(mf+mb) -> MB bf16
  mgemm(stream, 0, false, 0, pUB, 512, pWB + WB_OUT, 512, nullptr,
        pMO, nullptr, 256, nullptr, 8192, 256, 512);
  hipLaunchKernelGGL(k_layernorm2, dim3(4096), dim3(256), 0, stream, pMO, pMB, n2_g, n2_b);

  // 11) ff1 = gelu(m @ W_ff1^T + b) -> FF1B bf16 ; out = ff1 @ W_ff2^T + b + res
  mgemm(stream, 1, false, 1, pMB, 256, pWB + WB_FF1, 256, b_ff1,
        nullptr, pFF1B, 1024, nullptr, 4096, 1024, 256);
  mgemm(stream, 0, true, 0, pFF1B, 1024, pWB + WB_FF2, 1024, b_ff2,
        d_out, nullptr, 256, pRES, 4096, 256, 1024);
}